// Round 6
// baseline (527.546 us; speedup 1.0000x reference)
//
#include <hip/hip_runtime.h>

#define NN 100000
#define EE 1600000
#define BB 256
#define IN_F 7
#define HH 128
#define NBKT 391        // ceil(NN/256) buckets for binned CSR fill
#define BIN_CHUNK 4096  // edges per bin_edges2 block

typedef unsigned int uint;
typedef unsigned short ushort;
typedef __attribute__((ext_vector_type(8))) short short8;
typedef __attribute__((ext_vector_type(4))) short short4v;
typedef __attribute__((ext_vector_type(4))) float f32x4;

// ---------------- bf16 helpers ----------------

__device__ __forceinline__ float bflo(uint u) { return __uint_as_float(u << 16); }
__device__ __forceinline__ float bfhi(uint u) { return __uint_as_float(u & 0xFFFF0000u); }
__device__ __forceinline__ ushort f2bf(float x) {   // RNE; inputs finite
    uint u = __float_as_uint(x);
    u = (u + 0x7FFFu + ((u >> 16) & 1u)) >> 16;
    return (ushort)u;
}

// ---------------- CSR build ----------------

__global__ void count_deg(const int* __restrict__ ei, int* __restrict__ deg, int e) {
    int i = blockIdx.x * 256 + threadIdx.x;
    if (i < e) atomicAdd(&deg[ei[e + i]], 1);   // dst = ei[E + i]
}

__global__ void scan_partial(const int* __restrict__ deg, int* __restrict__ bsum, int n) {
    __shared__ int sd[256];
    int b = blockIdx.x, t = threadIdx.x;
    int base = b * 1024 + t * 4;
    int s = 0;
    #pragma unroll
    for (int k = 0; k < 4; ++k) { int i = base + k; if (i < n) s += deg[i]; }
    sd[t] = s; __syncthreads();
    for (int off = 128; off > 0; off >>= 1) {
        if (t < off) sd[t] += sd[t + off];
        __syncthreads();
    }
    if (t == 0) bsum[b] = sd[0];
}

__global__ void scan_bsum(int* __restrict__ bsum, int nb) {
    __shared__ int sd[256];
    int t = threadIdx.x;
    int v = (t < nb) ? bsum[t] : 0;
    sd[t] = v; __syncthreads();
    for (int off = 1; off < 256; off <<= 1) {
        int add = (t >= off) ? sd[t - off] : 0;
        __syncthreads();
        sd[t] += add;
        __syncthreads();
    }
    if (t < nb) bsum[t] = sd[t] - v;   // exclusive
}

// also writes bcur[b] = rowptr[b*256] (init_bcur folded in)
__global__ void scan_apply(const int* __restrict__ deg, const int* __restrict__ bsum,
                           int* __restrict__ rowptr, int* __restrict__ bcur, int n, int e) {
    __shared__ int sd[256];
    int b = blockIdx.x, t = threadIdx.x;
    int base = b * 1024 + t * 4;
    int v[4]; int s = 0;
    #pragma unroll
    for (int k = 0; k < 4; ++k) { int i = base + k; v[k] = (i < n) ? deg[i] : 0; s += v[k]; }
    sd[t] = s; __syncthreads();
    int mine = s;
    for (int off = 1; off < 256; off <<= 1) {
        int add = (t >= off) ? sd[t - off] : 0;
        __syncthreads();
        sd[t] += add;
        __syncthreads();
    }
    int run = sd[t] - mine + bsum[b];
    #pragma unroll
    for (int k = 0; k < 4; ++k) {
        int i = base + k;
        if (i < n) {
            rowptr[i] = run;
            if ((i & 255) == 0) bcur[i >> 8] = run;
        }
        run += v[k];
    }
    if (b == 0 && t == 0) rowptr[n] = e;
}

// Pass A (two-level): per-block LDS histogram of the 391 buckets, one global
// atomicAdd per (block,bucket) to reserve a range, then LDS-cursor scatter.
// Packed entry: src (17b) | (dst&255) << 17.
__global__ __launch_bounds__(256) void bin_edges2(const int* __restrict__ ei,
        int* __restrict__ bcur, int* __restrict__ ebuf, int e) {
    __shared__ int hist[NBKT];
    __shared__ int base[NBKT];
    int t = threadIdx.x;
    int start = blockIdx.x * BIN_CHUNK;
    int end = start + BIN_CHUNK; if (end > e) end = e;
    for (int b = t; b < NBKT; b += 256) hist[b] = 0;
    __syncthreads();
    for (int i = start + t; i < end; i += 256)
        atomicAdd(&hist[ei[e + i] >> 8], 1);
    __syncthreads();
    for (int b = t; b < NBKT; b += 256) {
        int c = hist[b];
        base[b] = (c > 0) ? atomicAdd(&bcur[b], c) : 0;
        hist[b] = 0;
    }
    __syncthreads();
    for (int i = start + t; i < end; i += 256) {
        int d = ei[e + i], s = ei[i];
        int b = d >> 8;
        int pos = base[b] + atomicAdd(&hist[b], 1);
        ebuf[pos] = s | ((d & 255) << 17);
    }
}

// Pass B: one block per bucket; LDS cursors; colarr writes confined to the
// bucket's contiguous CSR region.
__global__ __launch_bounds__(256) void distribute(const int* __restrict__ ebuf,
        const int* __restrict__ rowptr, int* __restrict__ colarr, int n) {
    __shared__ int cur[256];
    int b = blockIdx.x, t = threadIdx.x;
    int n0 = b * 256;
    int n1 = n0 + 256; if (n1 > n) n1 = n;
    if (n0 + t < n1) cur[t] = rowptr[n0 + t];
    __syncthreads();
    int ebeg = rowptr[n0], eend = rowptr[n1];
    for (int i = ebeg + t; i < eend; i += 256) {
        int v = ebuf[i];
        int pos = atomicAdd(&cur[(v >> 17) & 255], 1);
        colarr[pos] = v & 0x1FFFF;
    }
}

// ---------------- weight pre-split (all 8 matrices, one launch) ----------------
// MFMA B-fragment layout: lane holds B[k=(lane>>4)*8+j][n=lane&15], j=0..7.
// Storage: [(kc*8+nt)*64 + lane]*8 + j. hi=bf16(W), lo=bf16(W-hi).

__global__ void wsplit_all(
        const float* __restrict__ w0, const float* __restrict__ w1,
        const float* __restrict__ w2, const float* __restrict__ w3,
        const float* __restrict__ w4, const float* __restrict__ w5,
        const float* __restrict__ w6, const float* __restrict__ w7,
        ushort* __restrict__ hiB, ushort* __restrict__ loB) {
    const float* ws[8] = {w0, w1, w2, w3, w4, w5, w6, w7};
    int gidx = blockIdx.x * 256 + threadIdx.x;   // 0..131071
    int mi = gidx >> 14;
    int idx = gidx & 16383;
    int j = idx & 7, l = (idx >> 3) & 63, blk = idx >> 9;
    int kc = blk >> 3, nt = blk & 7;
    int k = kc * 32 + (l >> 4) * 8 + j;
    int n = nt * 16 + (l & 15);
    float f = ws[mi][k * 128 + n];
    ushort h = f2bf(f);
    float hf = __uint_as_float((uint)h << 16);
    hiB[gidx] = h;
    loB[gidx] = f2bf(f - hf);
}

// ---------------- layer-0 aggregation (d=7) ----------------

__global__ __launch_bounds__(256) void agg7(const float* __restrict__ xin,
        const int* __restrict__ rowptr, const int* __restrict__ colarr,
        float* __restrict__ h0, int n) {
    int node = blockIdx.x * 32 + (threadIdx.x >> 3);
    int f = threadIdx.x & 7;
    if (node >= n) return;
    int fidx = (f < 7) ? f : 0;
    float acc = xin[node * 7 + fidx];
    int beg = rowptr[node], end = rowptr[node + 1];
    int j = beg;
    for (; j + 4 <= end; j += 4) {
        int s0 = colarr[j], s1 = colarr[j+1], s2 = colarr[j+2], s3 = colarr[j+3];
        float v0 = xin[s0*7 + fidx], v1 = xin[s1*7 + fidx];
        float v2 = xin[s2*7 + fidx], v3 = xin[s3*7 + fidx];
        acc += (v0 + v1) + (v2 + v3);
    }
    for (; j < end; ++j) acc += xin[colarr[j]*7 + fidx];
    h0[node * 8 + f] = (f < 7) ? acc : 0.f;
}

// ---------------- small first linear (bf16 output, row-major XB0) ----------------

__global__ __launch_bounds__(256) void lin7(const float* __restrict__ h0,
        const float* __restrict__ W, const float* __restrict__ bias,
        ushort* __restrict__ out, int n) {
    __shared__ float wl[7][128];
    __shared__ float hl[8][8];
    int t = threadIdx.x;
    for (int l = t; l < 7 * 128; l += 256) wl[l >> 7][l & 127] = W[l];
    int row0 = blockIdx.x * 8;
    if (t < 64) {
        int r = t >> 3, k = t & 7;
        int gr = row0 + r;
        hl[r][k] = (gr < n) ? h0[gr * 8 + k] : 0.f;
    }
    __syncthreads();
    int c = t & 127, g = t >> 7;
    float bv = bias[c];
    #pragma unroll
    for (int i = 0; i < 4; ++i) {
        int r = g * 4 + i, gr = row0 + r;
        if (gr < n) {
            float acc = bv;
            #pragma unroll
            for (int k = 0; k < 7; ++k) acc += hl[r][k] * wl[k][c];
            out[gr * 128 + c] = f2bf(fmaxf(acc, 0.f));
        }
    }
}

// ---------------- XCD-pinned sliced aggregation (R19) ----------------
// X stored as 8 hi-bf16 planes [s][N][16] (3.2 MB/plane -> one XCD's 4 MB L2).
// Block (nb, s=blockIdx&7): consecutive blockIdx round-robin across the 8
// XCDs, pinning slice s's plane L2-resident. Output: hi/lo bf16 planes
// hb[2][8][N][16] = x_self + sum_nbr split for the MFMA MLP (numerics
// identical to the fused path: sum in f32, split once at write).

__global__ __launch_bounds__(256, 8) void gather_slice(
        const ushort* __restrict__ xbs,   // [8][n][16] hi planes
        const int* __restrict__ rowptr, const int* __restrict__ colarr,
        ushort* __restrict__ hb, int n)   // [2][8][n][16] hi/lo planes
{
    __shared__ int idx[2048];
    int t = threadIdx.x;
    int s = blockIdx.x & 7;
    int nb = blockIdx.x >> 3;
    int row0 = nb * 64;
    const ushort* plane = xbs + (size_t)s * n * 16;
    ushort* hhi = hb + (size_t)s * n * 16;
    ushort* hlo = hb + (size_t)(8 + s) * n * 16;

    int rlast = row0 + 64; if (rlast > n) rlast = n;
    int eb = rowptr[row0];
    int cnt = rowptr[rlast] - eb;
    int staged = cnt < 2048 ? cnt : 2048;
    for (int i = t; i < staged; i += 256) idx[i] = colarr[eb + i];
    __syncthreads();

    int r = t >> 2, q = t & 3;              // 4 threads/row, 4 bf16 cols each
    int gr = row0 + r;
    if (gr >= n) return;
    uint2 sv = ((const uint2*)(plane + (size_t)gr * 16))[q];
    float a0 = bflo(sv.x), a1 = bfhi(sv.x), a2 = bflo(sv.y), a3 = bfhi(sv.y);
    int beg = rowptr[gr] - eb, end = rowptr[gr + 1] - eb;
    int j = beg;
    for (; j + 2 <= end; j += 2) {
        int s0 = (j     < staged) ? idx[j]     : colarr[eb + j];
        int s1 = (j + 1 < staged) ? idx[j + 1] : colarr[eb + j + 1];
        uint2 v0 = ((const uint2*)(plane + (size_t)s0 * 16))[q];
        uint2 v1 = ((const uint2*)(plane + (size_t)s1 * 16))[q];
        a0 += bflo(v0.x) + bflo(v1.x);
        a1 += bfhi(v0.x) + bfhi(v1.x);
        a2 += bflo(v0.y) + bflo(v1.y);
        a3 += bfhi(v0.y) + bfhi(v1.y);
    }
    for (; j < end; ++j) {
        int s0 = (j < staged) ? idx[j] : colarr[eb + j];
        uint2 v = ((const uint2*)(plane + (size_t)s0 * 16))[q];
        a0 += bflo(v.x); a1 += bfhi(v.x); a2 += bflo(v.y); a3 += bfhi(v.y);
    }
    float av[4] = {a0, a1, a2, a3};
    short4v hi4, lo4;
    #pragma unroll
    for (int k = 0; k < 4; ++k) {
        ushort h = f2bf(av[k]);
        hi4[k] = (short)h;
        lo4[k] = (short)f2bf(av[k] - __uint_as_float((uint)h << 16));
    }
    *(short4v*)&hhi[(size_t)gr * 16 + q * 4] = hi4;
    *(short4v*)&hlo[(size_t)gr * 16 + q * 4] = lo4;
}

// ------- MFMA MLP + JK + pool (512 thr = 8 waves, 32-row / 16 KB tile) -------
// R19: gather removed (gather_slice feeds hbuf). INMODE 0 = row-major bf16
// (layer-0 XB0, lo=0). INMODE 1 = sliced hi/lo planes (hbuf) -> LDS staging
// is a pure copy, zero repack VALU. Epilogue WRITE_X emits sliced hi planes
// (wave w owns plane w since col = w*16+lm).

// element (r, cu) lives at bufHL[h][r][ ((cu>>3) ^ (r&7))*8 + (cu&7) ]
__device__ __forceinline__ int swch(int chunk, int r) { return chunk ^ (r & 7); }

__device__ __forceinline__ void gemm_mfma(
        const ushort* __restrict__ WH, const ushort* __restrict__ WL,
        const ushort (&bufHL)[2][32][128], int w, int lm, int lq, int l,
        f32x4 (&acc)[2])
{
    #pragma unroll
    for (int mi = 0; mi < 2; ++mi) acc[mi] = (f32x4){0.f, 0.f, 0.f, 0.f};
    const short8* BH = (const short8*)WH;
    const short8* BL = (const short8*)WL;
    #pragma unroll
    for (int kc = 0; kc < 4; ++kc) {
        short8 bh = BH[(kc * 8 + w) * 64 + l];
        short8 bl = BL[(kc * 8 + w) * 64 + l];
        #pragma unroll
        for (int mi = 0; mi < 2; ++mi) {
            int row = mi * 16 + lm;
            int ch = swch(kc * 4 + lq, row);
            short8 ah = *(const short8*)&bufHL[0][row][ch * 8];
            short8 al = *(const short8*)&bufHL[1][row][ch * 8];
            acc[mi] = __builtin_amdgcn_mfma_f32_16x16x32_bf16(ah, bh, acc[mi], 0, 0, 0);
            acc[mi] = __builtin_amdgcn_mfma_f32_16x16x32_bf16(al, bh, acc[mi], 0, 0, 0);
            acc[mi] = __builtin_amdgcn_mfma_f32_16x16x32_bf16(ah, bl, acc[mi], 0, 0, 0);
        }
    }
}

// relu + bias; write hi/lo back to LDS; optional SLICED hi-plane XB out
__device__ __forceinline__ void epi_store(f32x4 (&acc)[2], const float* __restrict__ bias,
        ushort (&bufHL)[2][32][128], int row0, int n, int w, int lm, int lq,
        ushort* __restrict__ xout)
{
    int col = w * 16 + lm;
    float bv = bias[col];
    #pragma unroll
    for (int mi = 0; mi < 2; ++mi) {
        #pragma unroll
        for (int rr = 0; rr < 4; ++rr) {
            int row = mi * 16 + lq * 4 + rr;
            int gr = row0 + row;
            float v = fmaxf(acc[mi][rr] + bv, 0.f);
            if (gr >= n) v = 0.f;
            ushort hi = f2bf(v);
            float hf = __uint_as_float((uint)hi << 16);
            ushort lo = f2bf(v - hf);
            int off = (swch(col >> 3, row) << 3) | (col & 7);
            bufHL[0][row][off] = hi;
            bufHL[1][row][off] = lo;
            if (xout != nullptr && gr < n)
                xout[(size_t)w * n * 16 + (size_t)gr * 16 + lm] = hi;
        }
    }
}

template<int INMODE, bool DO_A, bool LASTB, bool WRITE_X>
__global__ __launch_bounds__(512, 8) void mlp_fused(
        const ushort* __restrict__ in_bf,
        const ushort* __restrict__ WaH, const ushort* __restrict__ WaL,
        const float* __restrict__ ba,
        const ushort* __restrict__ WbH, const ushort* __restrict__ WbL,
        const float* __restrict__ bb,
        const ushort* __restrict__ WjH, const ushort* __restrict__ WjL,
        const float* __restrict__ bjk,
        const int* __restrict__ batch,
        ushort* __restrict__ xout_bf, float* __restrict__ pooled, int n)
{
    __shared__ __align__(16) ushort bufHL[2][32][128];   // 16 KB (hi | lo)
    int t = threadIdx.x;
    int row0 = blockIdx.x * 32;

    if (INMODE == 0) {
        // bf16 staging of t0: hi = input (already bf16), lo = 0; one chunk each
        int r = t >> 4, c = t & 15;
        int gr = row0 + r;
        uint4 v = make_uint4(0u, 0u, 0u, 0u);
        if (gr < n) v = *(const uint4*)&in_bf[(size_t)gr * 128 + c * 8];
        int ch = swch(c, r);
        *(uint4*)&bufHL[0][r][ch * 8] = v;
        *(uint4*)&bufHL[1][r][ch * 8] = make_uint4(0u, 0u, 0u, 0u);
    } else {
        // sliced hi/lo planes: 1024 x 16B chunks, pure copy
        #pragma unroll
        for (int it = 0; it < 2; ++it) {
            int cidx = t + it * 512;           // 0..1023
            int h = cidx >> 9, rem = cidx & 511;
            int p = rem >> 6, rr = (rem >> 1) & 31, half = rem & 1;
            int gr = row0 + rr;
            uint4 v = make_uint4(0u, 0u, 0u, 0u);
            if (gr < n)
                v = *(const uint4*)&in_bf[(size_t)(h * 8 + p) * n * 16
                                          + (size_t)gr * 16 + half * 8];
            *(uint4*)&bufHL[h][rr][swch(p * 2 + half, rr) * 8] = v;
        }
    }
    __syncthreads();

    int w = t >> 6, l = t & 63;
    int lm = l & 15, lq = l >> 4;
    f32x4 acc[2];

    if (DO_A) {
        gemm_mfma(WaH, WaL, bufHL, w, lm, lq, l, acc);
        __syncthreads();
        epi_store(acc, ba, bufHL, row0, n, w, lm, lq, nullptr);
        __syncthreads();
    }

    gemm_mfma(WbH, WbL, bufHL, w, lm, lq, l, acc);
    __syncthreads();
    epi_store(acc, bb, bufHL, row0, n, w, lm, lq, WRITE_X ? xout_bf : nullptr);
    __syncthreads();

    gemm_mfma(WjH, WjL, bufHL, w, lm, lq, l, acc);
    __syncthreads();

    // JK epilogue: +bjk (last layer), mask invalid rows, stage hi/lo into LDS
    {
        int col = w * 16 + lm;
        float bv = LASTB ? bjk[col] : 0.f;
        #pragma unroll
        for (int mi = 0; mi < 2; ++mi) {
            #pragma unroll
            for (int rr = 0; rr < 4; ++rr) {
                int row = mi * 16 + lq * 4 + rr;
                int gr = row0 + row;
                float v = acc[mi][rr] + bv;
                if (gr >= n) v = 0.f;
                ushort hi = f2bf(v);
                float hf = __uint_as_float((uint)hi << 16);
                ushort lo = f2bf(v - hf);
                int off = (swch(col >> 3, row) << 3) | (col & 7);
                bufHL[0][row][off] = hi;
                bufHL[1][row][off] = lo;
            }
        }
    }
    __syncthreads();

    // pooling (values decoded as hi+lo; ~2^-17 rel error, negligible)
    int row_last = row0 + 31; if (row_last > n - 1) row_last = n - 1;
    int g_first = batch[row0];
    int g_last  = batch[row_last];
    int c = t & 127, qh = t >> 7;   // 4 quarters x 8 rows
    if (g_first == g_last) {
        float sacc = 0.f;
        #pragma unroll 4
        for (int r = qh * 8; r < qh * 8 + 8; ++r) {
            int off = (swch(c >> 3, r) << 3) | (c & 7);
            sacc += __uint_as_float((uint)bufHL[0][r][off] << 16)
                  + __uint_as_float((uint)bufHL[1][r][off] << 16);
        }
        __syncthreads();
        float* scr = (float*)&bufHL[0][0][0];   // 512 floats scratch
        scr[t] = sacc;
        __syncthreads();
        if (t < 128)
            atomicAdd(&pooled[g_first * 128 + t],
                      (scr[t] + scr[t + 128]) + (scr[t + 256] + scr[t + 384]));
    } else {
        float sacc = 0.f; int gprev = -1;
        for (int r = qh * 8; r < qh * 8 + 8; ++r) {
            int gr = row0 + r;
            if (gr >= n) break;
            int g = batch[gr];
            if (g != gprev) {
                if (gprev >= 0) atomicAdd(&pooled[gprev * 128 + c], sacc);
                sacc = 0.f; gprev = g;
            }
            int off = (swch(c >> 3, r) << 3) | (c & 7);
            sacc += __uint_as_float((uint)bufHL[0][r][off] << 16)
                  + __uint_as_float((uint)bufHL[1][r][off] << 16);
        }
        if (gprev >= 0) atomicAdd(&pooled[gprev * 128 + c], sacc);
    }
}

// ---------------- classifier ----------------

__global__ __launch_bounds__(256) void classifier(const float* __restrict__ pooled,
        const float* __restrict__ Wc1, const float* __restrict__ bc1,
        const float* __restrict__ gamma, const float* __restrict__ beta,
        const float* __restrict__ rmean, const float* __restrict__ rvar,
        const float* __restrict__ Wc2, const float* __restrict__ bc2,
        float* __restrict__ out) {
    int g = blockIdx.x, t = threadIdx.x;
    __shared__ float p[128];
    __shared__ float r0[256], r1[256];
    if (t < 128) p[t] = pooled[g * 128 + t];
    __syncthreads();
    float acc = bc1[t];
    #pragma unroll 8
    for (int k = 0; k < 128; ++k) acc += p[k] * Wc1[k * 256 + t];
    float z = (acc - rmean[t]) * rsqrtf(rvar[t] + 1e-5f) * gamma[t] + beta[t];
    z = fmaxf(z, 0.f);
    r0[t] = z * Wc2[t * 2 + 0];
    r1[t] = z * Wc2[t * 2 + 1];
    __syncthreads();
    for (int s = 128; s > 0; s >>= 1) {
        if (t < s) { r0[t] += r0[t + s]; r1[t] += r1[t + s]; }
        __syncthreads();
    }
    if (t == 0) {
        out[g * 2 + 0] = r0[0] + bc2[0];
        out[g * 2 + 1] = r1[0] + bc2[1];
    }
}

// ---------------- launch ----------------

static inline size_t al256(size_t x) { return (x + 255) & ~size_t(255); }

extern "C" void kernel_launch(void* const* d_in, const int* in_sizes, int n_in,
                              void* d_out, int out_size, void* d_ws, size_t ws_size,
                              hipStream_t stream) {
    const float* x    = (const float*)d_in[0];
    const int*   ei   = (const int*)  d_in[1];
    const int*   batch= (const int*)  d_in[3];
    const float* W0a = (const float*)d_in[4];  const float* b0a = (const float*)d_in[5];
    const float* W0b = (const float*)d_in[6];  const float* b0b = (const float*)d_in[7];
    const float* W1a = (const float*)d_in[8];  const float* b1a = (const float*)d_in[9];
    const float* W1b = (const float*)d_in[10]; const float* b1b = (const float*)d_in[11];
    const float* W2a = (const float*)d_in[12]; const float* b2a = (const float*)d_in[13];
    const float* W2b = (const float*)d_in[14]; const float* b2b = (const float*)d_in[15];
    const float* Wjk = (const float*)d_in[16]; const float* bjk = (const float*)d_in[17];
    const float* Wc1 = (const float*)d_in[18]; const float* bc1 = (const float*)d_in[19];
    const float* gamma=(const float*)d_in[20]; const float* beta= (const float*)d_in[21];
    const float* rmean=(const float*)d_in[22]; const float* rvar= (const float*)d_in[23];
    const float* Wc2 = (const float*)d_in[24]; const float* bc2 = (const float*)d_in[25];
    float* out = (float*)d_out;

    const int N = NN, E = EE, B = BB;

    char* w = (char*)d_ws;
    size_t off = 0;
    int* deg    = (int*)(w + off); off = al256(off + (size_t)N * 4);
    int* rowptr = (int*)(w + off); off = al256(off + (size_t)(N + 1) * 4);
    int* bcur   = (int*)(w + off); off = al256(off + (size_t)NBKT * 4);
    int* colarr = (int*)(w + off); off = al256(off + (size_t)E * 4);
    int* ebuf   = (int*)(w + off); off = al256(off + (size_t)E * 4);
    int* bsum   = (int*)(w + off); off = al256(off + 1024 * 4);
    float* h0   = (float*)(w + off); off = al256(off + (size_t)N * 8 * 4);
    ushort* XB0 = (ushort*)(w + off); off = al256(off + (size_t)N * 128 * 2);   // row-major
    ushort* XB1s= (ushort*)(w + off); off = al256(off + (size_t)N * 128 * 2);   // sliced [8][N][16]
    ushort* XB2s= (ushort*)(w + off); off = al256(off + (size_t)N * 128 * 2);   // sliced [8][N][16]
    float* pooled = (float*)(w + off); off = al256(off + (size_t)B * 128 * 4);
    ushort* wfH = (ushort*)(w + off); off = al256(off + (size_t)8 * 16384 * 2);
    ushort* wfL = (ushort*)(w + off); off = al256(off + (size_t)8 * 16384 * 2);
    ushort* hbuf= (ushort*)(w + off); off = al256(off + (size_t)2 * N * 128 * 2); // hi/lo sliced

    hipMemsetAsync(deg, 0, (size_t)N * 4, stream);
    hipMemsetAsync(pooled, 0, (size_t)B * 128 * 4, stream);

    // pre-split weights (order: W0b, W1a, W1b, W2a, W2b, Wjk0, Wjk1, Wjk2)
    wsplit_all<<<512, 256, 0, stream>>>(W0b, W1a, W1b, W2a, W2b,
                                        Wjk, Wjk + 128 * 128, Wjk + 256 * 128,
                                        wfH, wfL);

    int nb = (N + 1023) / 1024;   // 98

    count_deg<<<(E + 255) / 256, 256, 0, stream>>>(ei, deg, E);
    scan_partial<<<nb, 256, 0, stream>>>(deg, bsum, N);
    scan_bsum<<<1, 256, 0, stream>>>(bsum, nb);
    scan_apply<<<nb, 256, 0, stream>>>(deg, bsum, rowptr, bcur, N, E);
    bin_edges2<<<(E + BIN_CHUNK - 1) / BIN_CHUNK, 256, 0, stream>>>(ei, bcur, ebuf, E);
    distribute<<<NBKT, 256, 0, stream>>>(ebuf, rowptr, colarr, N);

    int gLin = (N + 31) / 32;     // 3125 (mlp tiles)
    int gSl  = ((N + 63) / 64) * 8; // 12504 (gather_slice: 64-node groups x 8 slices)

    // Layer 0: agg7 -> lin7 (bf16 t0 -> XB0 row-major) -> mlp0, x1 -> XB1s (sliced)
    agg7<<<(N + 31) / 32, 256, 0, stream>>>(x, rowptr, colarr, h0, N);
    lin7<<<(N + 7) / 8, 256, 0, stream>>>(h0, W0a, b0a, XB0, N);
    mlp_fused<0, false, false, true><<<gLin, 512, 0, stream>>>(
        XB0,
        nullptr, nullptr, nullptr,
        wfH + 0 * 16384, wfL + 0 * 16384, b0b,
        wfH + 5 * 16384, wfL + 5 * 16384, nullptr,
        batch, XB1s, pooled, N);

    // Layer 1: XCD-sliced gather XB1s -> hbuf (hi/lo); MLP -> x2 -> XB2s
    gather_slice<<<gSl, 256, 0, stream>>>(XB1s, rowptr, colarr, hbuf, N);
    mlp_fused<1, true, false, true><<<gLin, 512, 0, stream>>>(
        hbuf,
        wfH + 1 * 16384, wfL + 1 * 16384, b1a,
        wfH + 2 * 16384, wfL + 2 * 16384, b1b,
        wfH + 6 * 16384, wfL + 6 * 16384, nullptr,
        batch, XB2s, pooled, N);

    // Layer 2: XCD-sliced gather XB2s -> hbuf; MLP -> jk2 (x3 never materialized)
    gather_slice<<<gSl, 256, 0, stream>>>(XB2s, rowptr, colarr, hbuf, N);
    mlp_fused<1, true, true, false><<<gLin, 512, 0, stream>>>(
        hbuf,
        wfH + 3 * 16384, wfL + 3 * 16384, b2a,
        wfH + 4 * 16384, wfL + 4 * 16384, b2b,
        wfH + 7 * 16384, wfL + 7 * 16384, bjk,
        batch, nullptr, pooled, N);

    classifier<<<B, 256, 0, stream>>>(pooled, Wc1, bc1, gamma, beta,
                                      rmean, rvar, Wc2, bc2, out);
}

// Round 7
// 443.472 us; speedup vs baseline: 1.1896x; 1.1896x over previous
//
#include <hip/hip_runtime.h>

#define NN 100000
#define EE 1600000
#define BB 256
#define IN_F 7
#define HH 128
#define NBKT 391        // ceil(NN/256) buckets for binned CSR fill
#define BIN_CHUNK 4096  // edges per bin_edges3 block
#define ESTRIDE 8192    // fixed ebuf capacity per bucket (mean 4096, sigma 64)

typedef unsigned int uint;
typedef unsigned short ushort;
typedef __attribute__((ext_vector_type(8))) short short8;
typedef __attribute__((ext_vector_type(4))) float f32x4;

// ---------------- bf16 helpers ----------------

__device__ __forceinline__ float bflo(uint u) { return __uint_as_float(u << 16); }
__device__ __forceinline__ float bfhi(uint u) { return __uint_as_float(u & 0xFFFF0000u); }
__device__ __forceinline__ ushort f2bf(float x) {   // RNE; inputs finite
    uint u = __float_as_uint(x);
    u = (u + 0x7FFFu + ((u >> 16) & 1u)) >> 16;
    return (ushort)u;
}

// ---------------- CSR build ----------------

__global__ void scan_partial(const int* __restrict__ deg, int* __restrict__ bsum, int n) {
    __shared__ int sd[256];
    int b = blockIdx.x, t = threadIdx.x;
    int base = b * 1024 + t * 4;
    int s = 0;
    #pragma unroll
    for (int k = 0; k < 4; ++k) { int i = base + k; if (i < n) s += deg[i]; }
    sd[t] = s; __syncthreads();
    for (int off = 128; off > 0; off >>= 1) {
        if (t < off) sd[t] += sd[t + off];
        __syncthreads();
    }
    if (t == 0) bsum[b] = sd[0];
}

__global__ void scan_bsum(int* __restrict__ bsum, int nb) {
    __shared__ int sd[256];
    int t = threadIdx.x;
    int v = (t < nb) ? bsum[t] : 0;
    sd[t] = v; __syncthreads();
    for (int off = 1; off < 256; off <<= 1) {
        int add = (t >= off) ? sd[t - off] : 0;
        __syncthreads();
        sd[t] += add;
        __syncthreads();
    }
    if (t < nb) bsum[t] = sd[t] - v;   // exclusive
}

__global__ void scan_apply(const int* __restrict__ deg, const int* __restrict__ bsum,
                           int* __restrict__ rowptr, int n, int e) {
    __shared__ int sd[256];
    int b = blockIdx.x, t = threadIdx.x;
    int base = b * 1024 + t * 4;
    int v[4]; int s = 0;
    #pragma unroll
    for (int k = 0; k < 4; ++k) { int i = base + k; v[k] = (i < n) ? deg[i] : 0; s += v[k]; }
    sd[t] = s; __syncthreads();
    int mine = s;
    for (int off = 1; off < 256; off <<= 1) {
        int add = (t >= off) ? sd[t - off] : 0;
        __syncthreads();
        sd[t] += add;
        __syncthreads();
    }
    int run = sd[t] - mine + bsum[b];
    #pragma unroll
    for (int k = 0; k < 4; ++k) {
        int i = base + k;
        if (i < n) rowptr[i] = run;
        run += v[k];
    }
    if (b == 0 && t == 0) rowptr[n] = e;
}

// R20: binning pass with fused per-node degree count (count_deg removed).
// ebuf uses FIXED bucket regions of ESTRIDE entries; bcur2 (zero-init) holds
// the per-bucket fill count. Packed entry: src (17b) | (dst&255) << 17.
__global__ __launch_bounds__(256) void bin_edges3(const int* __restrict__ ei,
        int* __restrict__ deg, int* __restrict__ bcur2, int* __restrict__ ebuf, int e) {
    __shared__ int hist[NBKT];
    __shared__ int base[NBKT];
    int t = threadIdx.x;
    int start = blockIdx.x * BIN_CHUNK;
    int end = start + BIN_CHUNK; if (end > e) end = e;
    for (int b = t; b < NBKT; b += 256) hist[b] = 0;
    __syncthreads();
    for (int i = start + t; i < end; i += 256) {
        int d = ei[e + i];
        atomicAdd(&hist[d >> 8], 1);
        atomicAdd(&deg[d], 1);
    }
    __syncthreads();
    for (int b = t; b < NBKT; b += 256) {
        int c = hist[b];
        base[b] = (c > 0) ? atomicAdd(&bcur2[b], c) : 0;
        hist[b] = 0;
    }
    __syncthreads();
    for (int i = start + t; i < end; i += 256) {
        int d = ei[e + i], s = ei[i];
        int b = d >> 8;
        int pos = base[b] + atomicAdd(&hist[b], 1);
        ebuf[b * ESTRIDE + pos] = s | ((d & 255) << 17);
    }
}

// one block per bucket; LDS cursors; colarr writes confined to the bucket's
// contiguous CSR region. Entry count read from bcur2.
__global__ __launch_bounds__(256) void distribute(const int* __restrict__ ebuf,
        const int* __restrict__ bcur2,
        const int* __restrict__ rowptr, int* __restrict__ colarr, int n) {
    __shared__ int cur[256];
    int b = blockIdx.x, t = threadIdx.x;
    int n0 = b * 256;
    int n1 = n0 + 256; if (n1 > n) n1 = n;
    if (n0 + t < n1) cur[t] = rowptr[n0 + t];
    __syncthreads();
    int cntb = bcur2[b];
    const int* src = ebuf + (size_t)b * ESTRIDE;
    for (int i = t; i < cntb; i += 256) {
        int v = src[i];
        int pos = atomicAdd(&cur[(v >> 17) & 255], 1);
        colarr[pos] = v & 0x1FFFF;
    }
}

// ---------------- weight pre-split (all 8 matrices, one launch) ----------------
// MFMA B-fragment layout: lane holds B[k=(lane>>4)*8+j][n=lane&15], j=0..7.
// Storage: [(kc*8+nt)*64 + lane]*8 + j. hi=bf16(W), lo=bf16(W-hi).

__global__ void wsplit_all(
        const float* __restrict__ w0, const float* __restrict__ w1,
        const float* __restrict__ w2, const float* __restrict__ w3,
        const float* __restrict__ w4, const float* __restrict__ w5,
        const float* __restrict__ w6, const float* __restrict__ w7,
        ushort* __restrict__ hiB, ushort* __restrict__ loB) {
    const float* ws[8] = {w0, w1, w2, w3, w4, w5, w6, w7};
    int gidx = blockIdx.x * 256 + threadIdx.x;   // 0..131071
    int mi = gidx >> 14;
    int idx = gidx & 16383;
    int j = idx & 7, l = (idx >> 3) & 63, blk = idx >> 9;
    int kc = blk >> 3, nt = blk & 7;
    int k = kc * 32 + (l >> 4) * 8 + j;
    int n = nt * 16 + (l & 15);
    float f = ws[mi][k * 128 + n];
    ushort h = f2bf(f);
    float hf = __uint_as_float((uint)h << 16);
    hiB[gidx] = h;
    loB[gidx] = f2bf(f - hf);
}

// ---------------- layer-0 aggregation (d=7) ----------------

__global__ __launch_bounds__(256) void agg7(const float* __restrict__ xin,
        const int* __restrict__ rowptr, const int* __restrict__ colarr,
        float* __restrict__ h0, int n) {
    int node = blockIdx.x * 32 + (threadIdx.x >> 3);
    int f = threadIdx.x & 7;
    if (node >= n) return;
    int fidx = (f < 7) ? f : 0;
    float acc = xin[node * 7 + fidx];
    int beg = rowptr[node], end = rowptr[node + 1];
    int j = beg;
    for (; j + 4 <= end; j += 4) {
        int s0 = colarr[j], s1 = colarr[j+1], s2 = colarr[j+2], s3 = colarr[j+3];
        float v0 = xin[s0*7 + fidx], v1 = xin[s1*7 + fidx];
        float v2 = xin[s2*7 + fidx], v3 = xin[s3*7 + fidx];
        acc += (v0 + v1) + (v2 + v3);
    }
    for (; j < end; ++j) acc += xin[colarr[j]*7 + fidx];
    h0[node * 8 + f] = (f < 7) ? acc : 0.f;
}

// ------- fused MLP + JK + pool (512 thr = 8 waves, 32-row / 16 KB tile) -------
// R20: INMODE 1 = bf16 gather from row-major XB (x4-unrolled, 4 outstanding
// uint4/lane). INMODE 2 = first layer: read h0 [n][8] + W0a/b0a, compute
// t0 = relu(h0@W0a+b0a) in-block (56 FMA/thread, K=7) -> hi/lo LDS. Replaces
// the lin7 kernel and the 51 MB XB0 round-trip.

// element (r, cu) lives at bufHL[h][r][ ((cu>>3) ^ (r&7))*8 + (cu&7) ]
__device__ __forceinline__ int swch(int chunk, int r) { return chunk ^ (r & 7); }

__device__ __forceinline__ void gemm_mfma(
        const ushort* __restrict__ WH, const ushort* __restrict__ WL,
        const ushort (&bufHL)[2][32][128], int w, int lm, int lq, int l,
        f32x4 (&acc)[2])
{
    #pragma unroll
    for (int mi = 0; mi < 2; ++mi) acc[mi] = (f32x4){0.f, 0.f, 0.f, 0.f};
    const short8* BH = (const short8*)WH;
    const short8* BL = (const short8*)WL;
    #pragma unroll
    for (int kc = 0; kc < 4; ++kc) {
        short8 bh = BH[(kc * 8 + w) * 64 + l];
        short8 bl = BL[(kc * 8 + w) * 64 + l];
        #pragma unroll
        for (int mi = 0; mi < 2; ++mi) {
            int row = mi * 16 + lm;
            int ch = swch(kc * 4 + lq, row);
            short8 ah = *(const short8*)&bufHL[0][row][ch * 8];
            short8 al = *(const short8*)&bufHL[1][row][ch * 8];
            acc[mi] = __builtin_amdgcn_mfma_f32_16x16x32_bf16(ah, bh, acc[mi], 0, 0, 0);
            acc[mi] = __builtin_amdgcn_mfma_f32_16x16x32_bf16(al, bh, acc[mi], 0, 0, 0);
            acc[mi] = __builtin_amdgcn_mfma_f32_16x16x32_bf16(ah, bl, acc[mi], 0, 0, 0);
        }
    }
}

// relu + bias; write hi/lo back to LDS; optional row-major bf16 XB out
__device__ __forceinline__ void epi_store(f32x4 (&acc)[2], const float* __restrict__ bias,
        ushort (&bufHL)[2][32][128], int row0, int n, int w, int lm, int lq,
        ushort* __restrict__ xout)
{
    int col = w * 16 + lm;
    float bv = bias[col];
    #pragma unroll
    for (int mi = 0; mi < 2; ++mi) {
        #pragma unroll
        for (int rr = 0; rr < 4; ++rr) {
            int row = mi * 16 + lq * 4 + rr;
            int gr = row0 + row;
            float v = fmaxf(acc[mi][rr] + bv, 0.f);
            if (gr >= n) v = 0.f;
            ushort hi = f2bf(v);
            float hf = __uint_as_float((uint)hi << 16);
            ushort lo = f2bf(v - hf);
            int off = (swch(col >> 3, row) << 3) | (col & 7);
            bufHL[0][row][off] = hi;
            bufHL[1][row][off] = lo;
            if (xout != nullptr && gr < n)
                xout[(size_t)gr * 128 + col] = hi;
        }
    }
}

template<int INMODE, bool DO_A, bool LASTB, bool WRITE_X>
__global__ __launch_bounds__(512, 8) void mlp_fused(
        const ushort* __restrict__ in_bf,
        const float* __restrict__ h0in, const float* __restrict__ W0a,
        const float* __restrict__ b0a,
        const int* __restrict__ rowptr, const int* __restrict__ colarr,
        const ushort* __restrict__ WaH, const ushort* __restrict__ WaL,
        const float* __restrict__ ba,
        const ushort* __restrict__ WbH, const ushort* __restrict__ WbL,
        const float* __restrict__ bb,
        const ushort* __restrict__ WjH, const ushort* __restrict__ WjL,
        const float* __restrict__ bjk,
        const int* __restrict__ batch,
        ushort* __restrict__ xout_bf, float* __restrict__ pooled, int n)
{
    __shared__ __align__(16) ushort bufHL[2][32][128];   // 16 KB (hi | lo)
    __shared__ float wlds[(INMODE == 2) ? 1024 : 1];     // W0a(896) + b0a(128)
    int t = threadIdx.x;
    int row0 = blockIdx.x * 32;

    if (INMODE == 1) {
        // LDS-staged indices; 16 threads/row, 1 uint4 chunk; x4 unroll.
        int* idx_lds = (int*)&bufHL[0][0][0];      // capacity 4096 ints (16 KB)
        int rlast = row0 + 32; if (rlast > n) rlast = n;
        int eb = rowptr[row0];
        int cnt = rowptr[rlast] - eb;
        int staged = cnt < 4096 ? cnt : 4096;
        for (int i = t; i < staged; i += 512) idx_lds[i] = colarr[eb + i];
        __syncthreads();

        int r = t >> 4, q = t & 15;
        int gr = row0 + r;
        float f[8];
        #pragma unroll
        for (int j = 0; j < 8; ++j) f[j] = 0.f;
        if (gr < n) {
            const uint4* sp = (const uint4*)(in_bf + (size_t)gr * 128);
            uint4 v = sp[q];
            f[0] = bflo(v.x); f[1] = bfhi(v.x);
            f[2] = bflo(v.y); f[3] = bfhi(v.y);
            f[4] = bflo(v.z); f[5] = bfhi(v.z);
            f[6] = bflo(v.w); f[7] = bfhi(v.w);
            int beg = rowptr[gr] - eb, end = rowptr[gr + 1] - eb;
            int j = beg;
            for (; j + 4 <= end; j += 4) {
                int s0 = (j     < staged) ? idx_lds[j]     : colarr[eb + j];
                int s1 = (j + 1 < staged) ? idx_lds[j + 1] : colarr[eb + j + 1];
                int s2 = (j + 2 < staged) ? idx_lds[j + 2] : colarr[eb + j + 2];
                int s3 = (j + 3 < staged) ? idx_lds[j + 3] : colarr[eb + j + 3];
                uint4 v0 = ((const uint4*)(in_bf + (size_t)s0 * 128))[q];
                uint4 v1 = ((const uint4*)(in_bf + (size_t)s1 * 128))[q];
                uint4 v2 = ((const uint4*)(in_bf + (size_t)s2 * 128))[q];
                uint4 v3 = ((const uint4*)(in_bf + (size_t)s3 * 128))[q];
                f[0] += (bflo(v0.x) + bflo(v1.x)) + (bflo(v2.x) + bflo(v3.x));
                f[1] += (bfhi(v0.x) + bfhi(v1.x)) + (bfhi(v2.x) + bfhi(v3.x));
                f[2] += (bflo(v0.y) + bflo(v1.y)) + (bflo(v2.y) + bflo(v3.y));
                f[3] += (bfhi(v0.y) + bfhi(v1.y)) + (bfhi(v2.y) + bfhi(v3.y));
                f[4] += (bflo(v0.z) + bflo(v1.z)) + (bflo(v2.z) + bflo(v3.z));
                f[5] += (bfhi(v0.z) + bfhi(v1.z)) + (bfhi(v2.z) + bfhi(v3.z));
                f[6] += (bflo(v0.w) + bflo(v1.w)) + (bflo(v2.w) + bflo(v3.w));
                f[7] += (bfhi(v0.w) + bfhi(v1.w)) + (bfhi(v2.w) + bfhi(v3.w));
            }
            for (; j < end; ++j) {
                int s0 = (j < staged) ? idx_lds[j] : colarr[eb + j];
                uint4 v2 = ((const uint4*)(in_bf + (size_t)s0 * 128))[q];
                f[0] += bflo(v2.x); f[1] += bfhi(v2.x);
                f[2] += bflo(v2.y); f[3] += bfhi(v2.y);
                f[4] += bflo(v2.z); f[5] += bfhi(v2.z);
                f[6] += bflo(v2.w); f[7] += bfhi(v2.w);
            }
        }
        __syncthreads();   // all idx_lds reads done before bufHL is overwritten
        {
            short8 hi8, lo8;
            #pragma unroll
            for (int j = 0; j < 8; ++j) {
                ushort h = f2bf(f[j]);
                hi8[j] = (short)h;
                float hf = __uint_as_float((uint)h << 16);
                lo8[j] = (short)f2bf(f[j] - hf);
            }
            int ch = swch(q, r);
            *(short8*)&bufHL[0][r][ch * 8] = hi8;
            *(short8*)&bufHL[1][r][ch * 8] = lo8;
        }
    } else {
        // INMODE 2: t0 = relu(h0 @ W0a + b0a), K=7, computed in-block.
        for (int l = t; l < 1024; l += 512)
            wlds[l] = (l < 896) ? W0a[l] : b0a[l - 896];
        __syncthreads();
        int r = t >> 4, cs = t & 15;          // row, 8-col chunk
        int gr = row0 + r;
        float h[7];
        #pragma unroll
        for (int k = 0; k < 7; ++k) h[k] = (gr < n) ? h0in[gr * 8 + k] : 0.f;
        float o[8];
        #pragma unroll
        for (int jj = 0; jj < 8; ++jj) {
            int c = cs * 8 + jj;
            float a = wlds[896 + c];
            #pragma unroll
            for (int k = 0; k < 7; ++k) a += h[k] * wlds[k * 128 + c];
            o[jj] = (gr < n) ? fmaxf(a, 0.f) : 0.f;
        }
        short8 hi8, lo8;
        #pragma unroll
        for (int jj = 0; jj < 8; ++jj) {
            ushort hh = f2bf(o[jj]);
            hi8[jj] = (short)hh;
            lo8[jj] = (short)f2bf(o[jj] - __uint_as_float((uint)hh << 16));
        }
        int ch = swch(cs, r);
        *(short8*)&bufHL[0][r][ch * 8] = hi8;
        *(short8*)&bufHL[1][r][ch * 8] = lo8;
    }
    __syncthreads();

    int w = t >> 6, l = t & 63;
    int lm = l & 15, lq = l >> 4;
    f32x4 acc[2];

    if (DO_A) {
        gemm_mfma(WaH, WaL, bufHL, w, lm, lq, l, acc);
        __syncthreads();
        epi_store(acc, ba, bufHL, row0, n, w, lm, lq, nullptr);
        __syncthreads();
    }

    gemm_mfma(WbH, WbL, bufHL, w, lm, lq, l, acc);
    __syncthreads();
    epi_store(acc, bb, bufHL, row0, n, w, lm, lq, WRITE_X ? xout_bf : nullptr);
    __syncthreads();

    gemm_mfma(WjH, WjL, bufHL, w, lm, lq, l, acc);
    __syncthreads();

    // JK epilogue: +bjk (last layer), mask invalid rows, stage hi/lo into LDS
    {
        int col = w * 16 + lm;
        float bv = LASTB ? bjk[col] : 0.f;
        #pragma unroll
        for (int mi = 0; mi < 2; ++mi) {
            #pragma unroll
            for (int rr = 0; rr < 4; ++rr) {
                int row = mi * 16 + lq * 4 + rr;
                int gr = row0 + row;
                float v = acc[mi][rr] + bv;
                if (gr >= n) v = 0.f;
                ushort hi = f2bf(v);
                float hf = __uint_as_float((uint)hi << 16);
                ushort lo = f2bf(v - hf);
                int off = (swch(col >> 3, row) << 3) | (col & 7);
                bufHL[0][row][off] = hi;
                bufHL[1][row][off] = lo;
            }
        }
    }
    __syncthreads();

    // pooling (values decoded as hi+lo; ~2^-17 rel error, negligible)
    int row_last = row0 + 31; if (row_last > n - 1) row_last = n - 1;
    int g_first = batch[row0];
    int g_last  = batch[row_last];
    int c = t & 127, qh = t >> 7;   // 4 quarters x 8 rows
    if (g_first == g_last) {
        float sacc = 0.f;
        #pragma unroll 4
        for (int r = qh * 8; r < qh * 8 + 8; ++r) {
            int off = (swch(c >> 3, r) << 3) | (c & 7);
            sacc += __uint_as_float((uint)bufHL[0][r][off] << 16)
                  + __uint_as_float((uint)bufHL[1][r][off] << 16);
        }
        __syncthreads();
        float* scr = (float*)&bufHL[0][0][0];   // 512 floats scratch
        scr[t] = sacc;
        __syncthreads();
        if (t < 128)
            atomicAdd(&pooled[g_first * 128 + t],
                      (scr[t] + scr[t + 128]) + (scr[t + 256] + scr[t + 384]));
    } else {
        float sacc = 0.f; int gprev = -1;
        for (int r = qh * 8; r < qh * 8 + 8; ++r) {
            int gr = row0 + r;
            if (gr >= n) break;
            int g = batch[gr];
            if (g != gprev) {
                if (gprev >= 0) atomicAdd(&pooled[gprev * 128 + c], sacc);
                sacc = 0.f; gprev = g;
            }
            int off = (swch(c >> 3, r) << 3) | (c & 7);
            sacc += __uint_as_float((uint)bufHL[0][r][off] << 16)
                  + __uint_as_float((uint)bufHL[1][r][off] << 16);
        }
        if (gprev >= 0) atomicAdd(&pooled[gprev * 128 + c], sacc);
    }
}

// ---------------- classifier ----------------

__global__ __launch_bounds__(256) void classifier(const float* __restrict__ pooled,
        const float* __restrict__ Wc1, const float* __restrict__ bc1,
        const float* __restrict__ gamma, const float* __restrict__ beta,
        const float* __restrict__ rmean, const float* __restrict__ rvar,
        const float* __restrict__ Wc2, const float* __restrict__ bc2,
        float* __restrict__ out) {
    int g = blockIdx.x, t = threadIdx.x;
    __shared__ float p[128];
    __shared__ float r0[256], r1[256];
    if (t < 128) p[t] = pooled[g * 128 + t];
    __syncthreads();
    float acc = bc1[t];
    #pragma unroll 8
    for (int k = 0; k < 128; ++k) acc += p[k] * Wc1[k * 256 + t];
    float z = (acc - rmean[t]) * rsqrtf(rvar[t] + 1e-5f) * gamma[t] + beta[t];
    z = fmaxf(z, 0.f);
    r0[t] = z * Wc2[t * 2 + 0];
    r1[t] = z * Wc2[t * 2 + 1];
    __syncthreads();
    for (int s = 128; s > 0; s >>= 1) {
        if (t < s) { r0[t] += r0[t + s]; r1[t] += r1[t + s]; }
        __syncthreads();
    }
    if (t == 0) {
        out[g * 2 + 0] = r0[0] + bc2[0];
        out[g * 2 + 1] = r1[0] + bc2[1];
    }
}

// ---------------- launch ----------------

static inline size_t al256(size_t x) { return (x + 255) & ~size_t(255); }

extern "C" void kernel_launch(void* const* d_in, const int* in_sizes, int n_in,
                              void* d_out, int out_size, void* d_ws, size_t ws_size,
                              hipStream_t stream) {
    const float* x    = (const float*)d_in[0];
    const int*   ei   = (const int*)  d_in[1];
    const int*   batch= (const int*)  d_in[3];
    const float* W0a = (const float*)d_in[4];  const float* b0a = (const float*)d_in[5];
    const float* W0b = (const float*)d_in[6];  const float* b0b = (const float*)d_in[7];
    const float* W1a = (const float*)d_in[8];  const float* b1a = (const float*)d_in[9];
    const float* W1b = (const float*)d_in[10]; const float* b1b = (const float*)d_in[11];
    const float* W2a = (const float*)d_in[12]; const float* b2a = (const float*)d_in[13];
    const float* W2b = (const float*)d_in[14]; const float* b2b = (const float*)d_in[15];
    const float* Wjk = (const float*)d_in[16]; const float* bjk = (const float*)d_in[17];
    const float* Wc1 = (const float*)d_in[18]; const float* bc1 = (const float*)d_in[19];
    const float* gamma=(const float*)d_in[20]; const float* beta= (const float*)d_in[21];
    const float* rmean=(const float*)d_in[22]; const float* rvar= (const float*)d_in[23];
    const float* Wc2 = (const float*)d_in[24]; const float* bc2 = (const float*)d_in[25];
    float* out = (float*)d_out;

    const int N = NN, E = EE, B = BB;

    char* w = (char*)d_ws;
    size_t off = 0;
    int* deg    = (int*)(w + off); off = al256(off + (size_t)N * 4);
    int* rowptr = (int*)(w + off); off = al256(off + (size_t)(N + 1) * 4);
    int* bcur2  = (int*)(w + off); off = al256(off + (size_t)NBKT * 4);
    int* colarr = (int*)(w + off); off = al256(off + (size_t)E * 4);
    int* ebuf   = (int*)(w + off); off = al256(off + (size_t)NBKT * ESTRIDE * 4);
    int* bsum   = (int*)(w + off); off = al256(off + 1024 * 4);
    float* h0   = (float*)(w + off); off = al256(off + (size_t)N * 8 * 4);
    ushort* XB1 = (ushort*)(w + off); off = al256(off + (size_t)N * 128 * 2);
    ushort* XB2 = (ushort*)(w + off); off = al256(off + (size_t)N * 128 * 2);
    float* pooled = (float*)(w + off); off = al256(off + (size_t)B * 128 * 4);
    ushort* wfH = (ushort*)(w + off); off = al256(off + (size_t)8 * 16384 * 2);
    ushort* wfL = (ushort*)(w + off); off = al256(off + (size_t)8 * 16384 * 2);

    hipMemsetAsync(deg, 0, (size_t)N * 4, stream);
    hipMemsetAsync(bcur2, 0, (size_t)NBKT * 4, stream);
    hipMemsetAsync(pooled, 0, (size_t)B * 128 * 4, stream);

    // pre-split weights (order: W0b, W1a, W1b, W2a, W2b, Wjk0, Wjk1, Wjk2)
    wsplit_all<<<512, 256, 0, stream>>>(W0b, W1a, W1b, W2a, W2b,
                                        Wjk, Wjk + 128 * 128, Wjk + 256 * 128,
                                        wfH, wfL);

    int nb = (N + 1023) / 1024;   // 98

    bin_edges3<<<(E + BIN_CHUNK - 1) / BIN_CHUNK, 256, 0, stream>>>(ei, deg, bcur2, ebuf, E);
    scan_partial<<<nb, 256, 0, stream>>>(deg, bsum, N);
    scan_bsum<<<1, 256, 0, stream>>>(bsum, nb);
    scan_apply<<<nb, 256, 0, stream>>>(deg, bsum, rowptr, N, E);
    distribute<<<NBKT, 256, 0, stream>>>(ebuf, bcur2, rowptr, colarr, N);

    int gLin = (N + 31) / 32;   // 3125

    // Layer 0: agg7 -> mlp0 (lin7 fused in, INMODE2), x1 -> XB1 (bf16)
    agg7<<<(N + 31) / 32, 256, 0, stream>>>(x, rowptr, colarr, h0, N);
    mlp_fused<2, false, false, true><<<gLin, 512, 0, stream>>>(
        nullptr, h0, W0a, b0a, rowptr, colarr,
        nullptr, nullptr, nullptr,
        wfH + 0 * 16384, wfL + 0 * 16384, b0b,
        wfH + 5 * 16384, wfL + 5 * 16384, nullptr,
        batch, XB1, pooled, N);

    // Layer 1: bf16 gather XB1 -> MLP -> x2 -> XB2 (bf16)
    mlp_fused<1, true, false, true><<<gLin, 512, 0, stream>>>(
        XB1, nullptr, nullptr, nullptr, rowptr, colarr,
        wfH + 1 * 16384, wfL + 1 * 16384, b1a,
        wfH + 2 * 16384, wfL + 2 * 16384, b1b,
        wfH + 6 * 16384, wfL + 6 * 16384, nullptr,
        batch, XB2, pooled, N);

    // Layer 2: bf16 gather XB2 -> MLP -> jk2 (x3 never materialized)
    mlp_fused<1, true, true, false><<<gLin, 512, 0, stream>>>(
        XB2, nullptr, nullptr, nullptr, rowptr, colarr,
        wfH + 3 * 16384, wfL + 3 * 16384, b2a,
        wfH + 4 * 16384, wfL + 4 * 16384, b2b,
        wfH + 7 * 16384, wfL + 7 * 16384, bjk,
        batch, nullptr, pooled, N);

    classifier<<<B, 256, 0, stream>>>(pooled, Wc1, bc1, gamma, beta,
                                      rmean, rvar, Wc2, bc2, out);
}

// Round 8
// 435.050 us; speedup vs baseline: 1.2126x; 1.0194x over previous
//
#include <hip/hip_runtime.h>

#define NN 100000
#define EE 1600000
#define BB 256
#define IN_F 7
#define HH 128
#define NBKT 391        // ceil(NN/256) buckets for binned CSR fill
#define BIN_CHUNK 4096  // edges per bin_edges3 block
#define ESTRIDE 8192    // fixed ebuf capacity per bucket (mean 4096, sigma 64)

typedef unsigned int uint;
typedef unsigned short ushort;
typedef __attribute__((ext_vector_type(8))) short short8;
typedef __attribute__((ext_vector_type(4))) float f32x4;

// ---------------- bf16 helpers ----------------

__device__ __forceinline__ float bflo(uint u) { return __uint_as_float(u << 16); }
__device__ __forceinline__ float bfhi(uint u) { return __uint_as_float(u & 0xFFFF0000u); }
__device__ __forceinline__ ushort f2bf(float x) {   // RNE; inputs finite
    uint u = __float_as_uint(x);
    u = (u + 0x7FFFu + ((u >> 16) & 1u)) >> 16;
    return (ushort)u;
}

// ---------------- CSR build ----------------

__global__ void scan_partial(const int* __restrict__ deg, int* __restrict__ bsum, int n) {
    __shared__ int sd[256];
    int b = blockIdx.x, t = threadIdx.x;
    int base = b * 1024 + t * 4;
    int s = 0;
    #pragma unroll
    for (int k = 0; k < 4; ++k) { int i = base + k; if (i < n) s += deg[i]; }
    sd[t] = s; __syncthreads();
    for (int off = 128; off > 0; off >>= 1) {
        if (t < off) sd[t] += sd[t + off];
        __syncthreads();
    }
    if (t == 0) bsum[b] = sd[0];
}

__global__ void scan_bsum(int* __restrict__ bsum, int nb) {
    __shared__ int sd[256];
    int t = threadIdx.x;
    int v = (t < nb) ? bsum[t] : 0;
    sd[t] = v; __syncthreads();
    for (int off = 1; off < 256; off <<= 1) {
        int add = (t >= off) ? sd[t - off] : 0;
        __syncthreads();
        sd[t] += add;
        __syncthreads();
    }
    if (t < nb) bsum[t] = sd[t] - v;   // exclusive
}

__global__ void scan_apply(const int* __restrict__ deg, const int* __restrict__ bsum,
                           int* __restrict__ rowptr, int n, int e) {
    __shared__ int sd[256];
    int b = blockIdx.x, t = threadIdx.x;
    int base = b * 1024 + t * 4;
    int v[4]; int s = 0;
    #pragma unroll
    for (int k = 0; k < 4; ++k) { int i = base + k; v[k] = (i < n) ? deg[i] : 0; s += v[k]; }
    sd[t] = s; __syncthreads();
    int mine = s;
    for (int off = 1; off < 256; off <<= 1) {
        int add = (t >= off) ? sd[t - off] : 0;
        __syncthreads();
        sd[t] += add;
        __syncthreads();
    }
    int run = sd[t] - mine + bsum[b];
    #pragma unroll
    for (int k = 0; k < 4; ++k) {
        int i = base + k;
        if (i < n) rowptr[i] = run;
        run += v[k];
    }
    if (b == 0 && t == 0) rowptr[n] = e;
}

// R21: binning pass with fused degree count; dst values staged in LDS during
// pass 1 so pass 2 reads only src from global (one fewer 6.4 MB ei pass).
// ebuf uses FIXED bucket regions of ESTRIDE entries; bcur2 (zero-init) holds
// the per-bucket fill count. Packed entry: src (17b) | (dst&255) << 17.
__global__ __launch_bounds__(256) void bin_edges3(const int* __restrict__ ei,
        int* __restrict__ deg, int* __restrict__ bcur2, int* __restrict__ ebuf, int e) {
    __shared__ int hist[NBKT];
    __shared__ int base[NBKT];
    __shared__ int dlds[BIN_CHUNK];
    int t = threadIdx.x;
    int start = blockIdx.x * BIN_CHUNK;
    int end = start + BIN_CHUNK; if (end > e) end = e;
    for (int b = t; b < NBKT; b += 256) hist[b] = 0;
    __syncthreads();
    for (int i = start + t; i < end; i += 256) {
        int d = ei[e + i];
        dlds[i - start] = d;
        atomicAdd(&hist[d >> 8], 1);
        atomicAdd(&deg[d], 1);
    }
    __syncthreads();
    for (int b = t; b < NBKT; b += 256) {
        int c = hist[b];
        base[b] = (c > 0) ? atomicAdd(&bcur2[b], c) : 0;
        hist[b] = 0;
    }
    __syncthreads();
    for (int i = start + t; i < end; i += 256) {
        int d = dlds[i - start], s = ei[i];
        int b = d >> 8;
        int pos = base[b] + atomicAdd(&hist[b], 1);
        ebuf[b * ESTRIDE + pos] = s | ((d & 255) << 17);
    }
}

// one block per bucket; LDS cursors; colarr writes confined to the bucket's
// contiguous CSR region. Entry count read from bcur2.
__global__ __launch_bounds__(256) void distribute(const int* __restrict__ ebuf,
        const int* __restrict__ bcur2,
        const int* __restrict__ rowptr, int* __restrict__ colarr, int n) {
    __shared__ int cur[256];
    int b = blockIdx.x, t = threadIdx.x;
    int n0 = b * 256;
    int n1 = n0 + 256; if (n1 > n) n1 = n;
    if (n0 + t < n1) cur[t] = rowptr[n0 + t];
    __syncthreads();
    int cntb = bcur2[b];
    const int* src = ebuf + (size_t)b * ESTRIDE;
    for (int i = t; i < cntb; i += 256) {
        int v = src[i];
        int pos = atomicAdd(&cur[(v >> 17) & 255], 1);
        colarr[pos] = v & 0x1FFFF;
    }
}

// ---------------- weight pre-split (all 8 matrices, one launch) ----------------
// MFMA B-fragment layout: lane holds B[k=(lane>>4)*8+j][n=lane&15], j=0..7.
// Storage: [(kc*8+nt)*64 + lane]*8 + j. hi=bf16(W), lo=bf16(W-hi).

__global__ void wsplit_all(
        const float* __restrict__ w0, const float* __restrict__ w1,
        const float* __restrict__ w2, const float* __restrict__ w3,
        const float* __restrict__ w4, const float* __restrict__ w5,
        const float* __restrict__ w6, const float* __restrict__ w7,
        ushort* __restrict__ hiB, ushort* __restrict__ loB) {
    const float* ws[8] = {w0, w1, w2, w3, w4, w5, w6, w7};
    int gidx = blockIdx.x * 256 + threadIdx.x;   // 0..131071
    int mi = gidx >> 14;
    int idx = gidx & 16383;
    int j = idx & 7, l = (idx >> 3) & 63, blk = idx >> 9;
    int kc = blk >> 3, nt = blk & 7;
    int k = kc * 32 + (l >> 4) * 8 + j;
    int n = nt * 16 + (l & 15);
    float f = ws[mi][k * 128 + n];
    ushort h = f2bf(f);
    float hf = __uint_as_float((uint)h << 16);
    hiB[gidx] = h;
    loB[gidx] = f2bf(f - hf);
}

// ---------------- layer-0 aggregation (d=7) ----------------

__global__ __launch_bounds__(256) void agg7(const float* __restrict__ xin,
        const int* __restrict__ rowptr, const int* __restrict__ colarr,
        float* __restrict__ h0, int n) {
    int node = blockIdx.x * 32 + (threadIdx.x >> 3);
    int f = threadIdx.x & 7;
    if (node >= n) return;
    int fidx = (f < 7) ? f : 0;
    float acc = xin[node * 7 + fidx];
    int beg = rowptr[node], end = rowptr[node + 1];
    int j = beg;
    for (; j + 4 <= end; j += 4) {
        int s0 = colarr[j], s1 = colarr[j+1], s2 = colarr[j+2], s3 = colarr[j+3];
        float v0 = xin[s0*7 + fidx], v1 = xin[s1*7 + fidx];
        float v2 = xin[s2*7 + fidx], v3 = xin[s3*7 + fidx];
        acc += (v0 + v1) + (v2 + v3);
    }
    for (; j < end; ++j) acc += xin[colarr[j]*7 + fidx];
    h0[node * 8 + f] = (f < 7) ? acc : 0.f;
}

// ------- fused MLP + JK + pool (512 thr = 8 waves, 32-row / 16 KB tile) -------
// R21: JK pooling moved from LDS to registers. Each thread's acc[2][4] covers
// ONE column over rows {mi*16 + lq*4 + rr}; the 4 lq-lanes of a wave tile all
// 32 rows, so shfl_xor(16)+shfl_xor(32) yields the column sum in-register ->
// one atomic per column. Kills the JK hi/lo LDS write, the pool decode pass,
// and 3 barriers. Gather loop: uniform staged/fallback branch (no per-iter
// selects).

// element (r, cu) lives at bufHL[h][r][ ((cu>>3) ^ (r&7))*8 + (cu&7) ]
__device__ __forceinline__ int swch(int chunk, int r) { return chunk ^ (r & 7); }

__device__ __forceinline__ void gemm_mfma(
        const ushort* __restrict__ WH, const ushort* __restrict__ WL,
        const ushort (&bufHL)[2][32][128], int w, int lm, int lq, int l,
        f32x4 (&acc)[2])
{
    #pragma unroll
    for (int mi = 0; mi < 2; ++mi) acc[mi] = (f32x4){0.f, 0.f, 0.f, 0.f};
    const short8* BH = (const short8*)WH;
    const short8* BL = (const short8*)WL;
    #pragma unroll
    for (int kc = 0; kc < 4; ++kc) {
        short8 bh = BH[(kc * 8 + w) * 64 + l];
        short8 bl = BL[(kc * 8 + w) * 64 + l];
        #pragma unroll
        for (int mi = 0; mi < 2; ++mi) {
            int row = mi * 16 + lm;
            int ch = swch(kc * 4 + lq, row);
            short8 ah = *(const short8*)&bufHL[0][row][ch * 8];
            short8 al = *(const short8*)&bufHL[1][row][ch * 8];
            acc[mi] = __builtin_amdgcn_mfma_f32_16x16x32_bf16(ah, bh, acc[mi], 0, 0, 0);
            acc[mi] = __builtin_amdgcn_mfma_f32_16x16x32_bf16(al, bh, acc[mi], 0, 0, 0);
            acc[mi] = __builtin_amdgcn_mfma_f32_16x16x32_bf16(ah, bl, acc[mi], 0, 0, 0);
        }
    }
}

// relu + bias; write hi/lo back to LDS; optional row-major bf16 XB out
__device__ __forceinline__ void epi_store(f32x4 (&acc)[2], const float* __restrict__ bias,
        ushort (&bufHL)[2][32][128], int row0, int n, int w, int lm, int lq,
        ushort* __restrict__ xout)
{
    int col = w * 16 + lm;
    float bv = bias[col];
    #pragma unroll
    for (int mi = 0; mi < 2; ++mi) {
        #pragma unroll
        for (int rr = 0; rr < 4; ++rr) {
            int row = mi * 16 + lq * 4 + rr;
            int gr = row0 + row;
            float v = fmaxf(acc[mi][rr] + bv, 0.f);
            if (gr >= n) v = 0.f;
            ushort hi = f2bf(v);
            float hf = __uint_as_float((uint)hi << 16);
            ushort lo = f2bf(v - hf);
            int off = (swch(col >> 3, row) << 3) | (col & 7);
            bufHL[0][row][off] = hi;
            bufHL[1][row][off] = lo;
            if (xout != nullptr && gr < n)
                xout[(size_t)gr * 128 + col] = hi;
        }
    }
}

template<int INMODE, bool DO_A, bool LASTB, bool WRITE_X>
__global__ __launch_bounds__(512, 8) void mlp_fused(
        const ushort* __restrict__ in_bf,
        const float* __restrict__ h0in, const float* __restrict__ W0a,
        const float* __restrict__ b0a,
        const int* __restrict__ rowptr, const int* __restrict__ colarr,
        const ushort* __restrict__ WaH, const ushort* __restrict__ WaL,
        const float* __restrict__ ba,
        const ushort* __restrict__ WbH, const ushort* __restrict__ WbL,
        const float* __restrict__ bb,
        const ushort* __restrict__ WjH, const ushort* __restrict__ WjL,
        const float* __restrict__ bjk,
        const int* __restrict__ batch,
        ushort* __restrict__ xout_bf, float* __restrict__ pooled, int n)
{
    __shared__ __align__(16) ushort bufHL[2][32][128];   // 16 KB (hi | lo)
    __shared__ float wlds[(INMODE == 2) ? 1024 : 1];     // W0a(896) + b0a(128)
    int t = threadIdx.x;
    int row0 = blockIdx.x * 32;

    if (INMODE == 1) {
        // LDS-staged indices; 16 threads/row, 1 uint4 chunk; x4 unroll.
        int* idx_lds = (int*)&bufHL[0][0][0];      // capacity 4096 ints (16 KB)
        int rlast = row0 + 32; if (rlast > n) rlast = n;
        int eb = rowptr[row0];
        int cnt = rowptr[rlast] - eb;
        bool allstaged = (cnt <= 4096);
        int staged = allstaged ? cnt : 0;
        for (int i = t; i < staged; i += 512) idx_lds[i] = colarr[eb + i];
        __syncthreads();

        int r = t >> 4, q = t & 15;
        int gr = row0 + r;
        float f[8];
        #pragma unroll
        for (int j = 0; j < 8; ++j) f[j] = 0.f;
        if (gr < n) {
            const uint4* sp = (const uint4*)(in_bf + (size_t)gr * 128);
            uint4 v = sp[q];
            f[0] = bflo(v.x); f[1] = bfhi(v.x);
            f[2] = bflo(v.y); f[3] = bfhi(v.y);
            f[4] = bflo(v.z); f[5] = bfhi(v.z);
            f[6] = bflo(v.w); f[7] = bfhi(v.w);
            int beg = rowptr[gr] - eb, end = rowptr[gr + 1] - eb;
            if (allstaged) {
                int j = beg;
                for (; j + 4 <= end; j += 4) {
                    int s0 = idx_lds[j],     s1 = idx_lds[j + 1];
                    int s2 = idx_lds[j + 2], s3 = idx_lds[j + 3];
                    uint4 v0 = ((const uint4*)(in_bf + (size_t)s0 * 128))[q];
                    uint4 v1 = ((const uint4*)(in_bf + (size_t)s1 * 128))[q];
                    uint4 v2 = ((const uint4*)(in_bf + (size_t)s2 * 128))[q];
                    uint4 v3 = ((const uint4*)(in_bf + (size_t)s3 * 128))[q];
                    f[0] += (bflo(v0.x) + bflo(v1.x)) + (bflo(v2.x) + bflo(v3.x));
                    f[1] += (bfhi(v0.x) + bfhi(v1.x)) + (bfhi(v2.x) + bfhi(v3.x));
                    f[2] += (bflo(v0.y) + bflo(v1.y)) + (bflo(v2.y) + bflo(v3.y));
                    f[3] += (bfhi(v0.y) + bfhi(v1.y)) + (bfhi(v2.y) + bfhi(v3.y));
                    f[4] += (bflo(v0.z) + bflo(v1.z)) + (bflo(v2.z) + bflo(v3.z));
                    f[5] += (bfhi(v0.z) + bfhi(v1.z)) + (bfhi(v2.z) + bfhi(v3.z));
                    f[6] += (bflo(v0.w) + bflo(v1.w)) + (bflo(v2.w) + bflo(v3.w));
                    f[7] += (bfhi(v0.w) + bfhi(v1.w)) + (bfhi(v2.w) + bfhi(v3.w));
                }
                for (; j < end; ++j) {
                    int s0 = idx_lds[j];
                    uint4 v2 = ((const uint4*)(in_bf + (size_t)s0 * 128))[q];
                    f[0] += bflo(v2.x); f[1] += bfhi(v2.x);
                    f[2] += bflo(v2.y); f[3] += bfhi(v2.y);
                    f[4] += bflo(v2.z); f[5] += bfhi(v2.z);
                    f[6] += bflo(v2.w); f[7] += bfhi(v2.w);
                }
            } else {
                for (int j = beg; j < end; ++j) {
                    int s0 = colarr[eb + j];
                    uint4 v2 = ((const uint4*)(in_bf + (size_t)s0 * 128))[q];
                    f[0] += bflo(v2.x); f[1] += bfhi(v2.x);
                    f[2] += bflo(v2.y); f[3] += bfhi(v2.y);
                    f[4] += bflo(v2.z); f[5] += bfhi(v2.z);
                    f[6] += bflo(v2.w); f[7] += bfhi(v2.w);
                }
            }
        }
        __syncthreads();   // all idx_lds reads done before bufHL is overwritten
        {
            short8 hi8, lo8;
            #pragma unroll
            for (int j = 0; j < 8; ++j) {
                ushort h = f2bf(f[j]);
                hi8[j] = (short)h;
                float hf = __uint_as_float((uint)h << 16);
                lo8[j] = (short)f2bf(f[j] - hf);
            }
            int ch = swch(q, r);
            *(short8*)&bufHL[0][r][ch * 8] = hi8;
            *(short8*)&bufHL[1][r][ch * 8] = lo8;
        }
    } else {
        // INMODE 2: t0 = relu(h0 @ W0a + b0a), K=7, computed in-block.
        for (int l = t; l < 1024; l += 512)
            wlds[l] = (l < 896) ? W0a[l] : b0a[l - 896];
        __syncthreads();
        int r = t >> 4, cs = t & 15;          // row, 8-col chunk
        int gr = row0 + r;
        float h[7];
        #pragma unroll
        for (int k = 0; k < 7; ++k) h[k] = (gr < n) ? h0in[gr * 8 + k] : 0.f;
        float o[8];
        #pragma unroll
        for (int jj = 0; jj < 8; ++jj) {
            int c = cs * 8 + jj;
            float a = wlds[896 + c];
            #pragma unroll
            for (int k = 0; k < 7; ++k) a += h[k] * wlds[k * 128 + c];
            o[jj] = (gr < n) ? fmaxf(a, 0.f) : 0.f;
        }
        short8 hi8, lo8;
        #pragma unroll
        for (int jj = 0; jj < 8; ++jj) {
            ushort hh = f2bf(o[jj]);
            hi8[jj] = (short)hh;
            lo8[jj] = (short)f2bf(o[jj] - __uint_as_float((uint)hh << 16));
        }
        int ch = swch(cs, r);
        *(short8*)&bufHL[0][r][ch * 8] = hi8;
        *(short8*)&bufHL[1][r][ch * 8] = lo8;
    }
    __syncthreads();

    int w = t >> 6, l = t & 63;
    int lm = l & 15, lq = l >> 4;
    f32x4 acc[2];

    if (DO_A) {
        gemm_mfma(WaH, WaL, bufHL, w, lm, lq, l, acc);
        __syncthreads();
        epi_store(acc, ba, bufHL, row0, n, w, lm, lq, nullptr);
        __syncthreads();
    }

    gemm_mfma(WbH, WbL, bufHL, w, lm, lq, l, acc);
    __syncthreads();
    epi_store(acc, bb, bufHL, row0, n, w, lm, lq, WRITE_X ? xout_bf : nullptr);
    __syncthreads();

    gemm_mfma(WjH, WjL, bufHL, w, lm, lq, l, acc);
    // no LDS use after this point -> no barrier; pool from registers.

    int colj = w * 16 + lm;
    float bvj = LASTB ? bjk[colj] : 0.f;
    float jv[2][4];
    #pragma unroll
    for (int mi = 0; mi < 2; ++mi) {
        #pragma unroll
        for (int rr = 0; rr < 4; ++rr) {
            int gr = row0 + mi * 16 + lq * 4 + rr;
            jv[mi][rr] = (gr < n) ? acc[mi][rr] + bvj : 0.f;
        }
    }
    int row_last = row0 + 31; if (row_last > n - 1) row_last = n - 1;
    int g_first = batch[row0];
    int g_last  = batch[row_last];
    if (g_first == g_last) {
        float s8 = ((jv[0][0] + jv[0][1]) + (jv[0][2] + jv[0][3]))
                 + ((jv[1][0] + jv[1][1]) + (jv[1][2] + jv[1][3]));
        s8 += __shfl_xor(s8, 16);
        s8 += __shfl_xor(s8, 32);
        if (lq == 0) atomicAdd(&pooled[g_first * 128 + colj], s8);
    } else {
        #pragma unroll
        for (int mi = 0; mi < 2; ++mi) {
            int rbase = row0 + mi * 16 + lq * 4;
            int gprev = batch[(rbase <= row_last) ? rbase : row_last];
            float run = 0.f;
            #pragma unroll
            for (int rr = 0; rr < 4; ++rr) {
                int gr = rbase + rr;
                int g = batch[(gr <= row_last) ? gr : row_last];
                if (g != gprev) {
                    atomicAdd(&pooled[gprev * 128 + colj], run);
                    run = 0.f; gprev = g;
                }
                run += jv[mi][rr];
            }
            atomicAdd(&pooled[gprev * 128 + colj], run);
        }
    }
}

// ---------------- classifier ----------------

__global__ __launch_bounds__(256) void classifier(const float* __restrict__ pooled,
        const float* __restrict__ Wc1, const float* __restrict__ bc1,
        const float* __restrict__ gamma, const float* __restrict__ beta,
        const float* __restrict__ rmean, const float* __restrict__ rvar,
        const float* __restrict__ Wc2, const float* __restrict__ bc2,
        float* __restrict__ out) {
    int g = blockIdx.x, t = threadIdx.x;
    __shared__ float p[128];
    __shared__ float r0[256], r1[256];
    if (t < 128) p[t] = pooled[g * 128 + t];
    __syncthreads();
    float acc = bc1[t];
    #pragma unroll 8
    for (int k = 0; k < 128; ++k) acc += p[k] * Wc1[k * 256 + t];
    float z = (acc - rmean[t]) * rsqrtf(rvar[t] + 1e-5f) * gamma[t] + beta[t];
    z = fmaxf(z, 0.f);
    r0[t] = z * Wc2[t * 2 + 0];
    r1[t] = z * Wc2[t * 2 + 1];
    __syncthreads();
    for (int s = 128; s > 0; s >>= 1) {
        if (t < s) { r0[t] += r0[t + s]; r1[t] += r1[t + s]; }
        __syncthreads();
    }
    if (t == 0) {
        out[g * 2 + 0] = r0[0] + bc2[0];
        out[g * 2 + 1] = r1[0] + bc2[1];
    }
}

// ---------------- launch ----------------

static inline size_t al256(size_t x) { return (x + 255) & ~size_t(255); }

extern "C" void kernel_launch(void* const* d_in, const int* in_sizes, int n_in,
                              void* d_out, int out_size, void* d_ws, size_t ws_size,
                              hipStream_t stream) {
    const float* x    = (const float*)d_in[0];
    const int*   ei   = (const int*)  d_in[1];
    const int*   batch= (const int*)  d_in[3];
    const float* W0a = (const float*)d_in[4];  const float* b0a = (const float*)d_in[5];
    const float* W0b = (const float*)d_in[6];  const float* b0b = (const float*)d_in[7];
    const float* W1a = (const float*)d_in[8];  const float* b1a = (const float*)d_in[9];
    const float* W1b = (const float*)d_in[10]; const float* b1b = (const float*)d_in[11];
    const float* W2a = (const float*)d_in[12]; const float* b2a = (const float*)d_in[13];
    const float* W2b = (const float*)d_in[14]; const float* b2b = (const float*)d_in[15];
    const float* Wjk = (const float*)d_in[16]; const float* bjk = (const float*)d_in[17];
    const float* Wc1 = (const float*)d_in[18]; const float* bc1 = (const float*)d_in[19];
    const float* gamma=(const float*)d_in[20]; const float* beta= (const float*)d_in[21];
    const float* rmean=(const float*)d_in[22]; const float* rvar= (const float*)d_in[23];
    const float* Wc2 = (const float*)d_in[24]; const float* bc2 = (const float*)d_in[25];
    float* out = (float*)d_out;

    const int N = NN, E = EE, B = BB;

    char* w = (char*)d_ws;
    size_t off = 0;
    int* deg    = (int*)(w + off); off = al256(off + (size_t)N * 4);
    int* rowptr = (int*)(w + off); off = al256(off + (size_t)(N + 1) * 4);
    int* bcur2  = (int*)(w + off); off = al256(off + (size_t)NBKT * 4);
    int* colarr = (int*)(w + off); off = al256(off + (size_t)E * 4);
    int* ebuf   = (int*)(w + off); off = al256(off + (size_t)NBKT * ESTRIDE * 4);
    int* bsum   = (int*)(w + off); off = al256(off + 1024 * 4);
    float* h0   = (float*)(w + off); off = al256(off + (size_t)N * 8 * 4);
    ushort* XB1 = (ushort*)(w + off); off = al256(off + (size_t)N * 128 * 2);
    ushort* XB2 = (ushort*)(w + off); off = al256(off + (size_t)N * 128 * 2);
    float* pooled = (float*)(w + off); off = al256(off + (size_t)B * 128 * 4);
    ushort* wfH = (ushort*)(w + off); off = al256(off + (size_t)8 * 16384 * 2);
    ushort* wfL = (ushort*)(w + off); off = al256(off + (size_t)8 * 16384 * 2);

    hipMemsetAsync(deg, 0, (size_t)N * 4, stream);
    hipMemsetAsync(bcur2, 0, (size_t)NBKT * 4, stream);
    hipMemsetAsync(pooled, 0, (size_t)B * 128 * 4, stream);

    // pre-split weights (order: W0b, W1a, W1b, W2a, W2b, Wjk0, Wjk1, Wjk2)
    wsplit_all<<<512, 256, 0, stream>>>(W0b, W1a, W1b, W2a, W2b,
                                        Wjk, Wjk + 128 * 128, Wjk + 256 * 128,
                                        wfH, wfL);

    int nb = (N + 1023) / 1024;   // 98

    bin_edges3<<<(E + BIN_CHUNK - 1) / BIN_CHUNK, 256, 0, stream>>>(ei, deg, bcur2, ebuf, E);
    scan_partial<<<nb, 256, 0, stream>>>(deg, bsum, N);
    scan_bsum<<<1, 256, 0, stream>>>(bsum, nb);
    scan_apply<<<nb, 256, 0, stream>>>(deg, bsum, rowptr, N, E);
    distribute<<<NBKT, 256, 0, stream>>>(ebuf, bcur2, rowptr, colarr, N);

    int gLin = (N + 31) / 32;   // 3125

    // Layer 0: agg7 -> mlp0 (lin7 fused in, INMODE2), x1 -> XB1 (bf16)
    agg7<<<(N + 31) / 32, 256, 0, stream>>>(x, rowptr, colarr, h0, N);
    mlp_fused<2, false, false, true><<<gLin, 512, 0, stream>>>(
        nullptr, h0, W0a, b0a, rowptr, colarr,
        nullptr, nullptr, nullptr,
        wfH + 0 * 16384, wfL + 0 * 16384, b0b,
        wfH + 5 * 16384, wfL + 5 * 16384, nullptr,
        batch, XB1, pooled, N);

    // Layer 1: bf16 gather XB1 -> MLP -> x2 -> XB2 (bf16)
    mlp_fused<1, true, false, true><<<gLin, 512, 0, stream>>>(
        XB1, nullptr, nullptr, nullptr, rowptr, colarr,
        wfH + 1 * 16384, wfL + 1 * 16384, b1a,
        wfH + 2 * 16384, wfL + 2 * 16384, b1b,
        wfH + 6 * 16384, wfL + 6 * 16384, nullptr,
        batch, XB2, pooled, N);

    // Layer 2: bf16 gather XB2 -> MLP -> jk2 (x3 never materialized)
    mlp_fused<1, true, true, false><<<gLin, 512, 0, stream>>>(
        XB2, nullptr, nullptr, nullptr, rowptr, colarr,
        wfH + 3 * 16384, wfL + 3 * 16384, b2a,
        wfH + 4 * 16384, wfL + 4 * 16384, b2b,
        wfH + 7 * 16384, wfL + 7 * 16384, bjk,
        batch, nullptr, pooled, N);

    classifier<<<B, 256, 0, stream>>>(pooled, Wc1, bc1, gamma, beta,
                                      rmean, rvar, Wc2, bc2, out);
}

// Round 9
// 389.017 us; speedup vs baseline: 1.3561x; 1.1183x over previous
//
#include <hip/hip_runtime.h>

#define NN 100000
#define EE 1600000
#define BB 256
#define IN_F 7
#define HH 128
#define NBKT 391        // ceil(NN/256) buckets for binned CSR fill
#define BIN_CHUNK 4096  // edges per bin_edges4 block
#define ESTRIDE 8192    // fixed ebuf capacity per bucket (mean 4096, sigma 64)

typedef unsigned int uint;
typedef unsigned short ushort;
typedef __attribute__((ext_vector_type(8))) short short8;
typedef __attribute__((ext_vector_type(4))) float f32x4;

// ---------------- bf16 helpers ----------------

__device__ __forceinline__ float bflo(uint u) { return __uint_as_float(u << 16); }
__device__ __forceinline__ float bfhi(uint u) { return __uint_as_float(u & 0xFFFF0000u); }
__device__ __forceinline__ ushort f2bf(float x) {   // RNE; inputs finite
    uint u = __float_as_uint(x);
    u = (u + 0x7FFFu + ((u >> 16) & 1u)) >> 16;
    return (ushort)u;
}

// ---------------- CSR build ----------------

__global__ void scan_partial(const int* __restrict__ deg, int* __restrict__ bsum, int n) {
    __shared__ int sd[256];
    int b = blockIdx.x, t = threadIdx.x;
    int base = b * 1024 + t * 4;
    int s = 0;
    #pragma unroll
    for (int k = 0; k < 4; ++k) { int i = base + k; if (i < n) s += deg[i]; }
    sd[t] = s; __syncthreads();
    for (int off = 128; off > 0; off >>= 1) {
        if (t < off) sd[t] += sd[t + off];
        __syncthreads();
    }
    if (t == 0) bsum[b] = sd[0];
}

__global__ void scan_bsum(int* __restrict__ bsum, int nb) {
    __shared__ int sd[256];
    int t = threadIdx.x;
    int v = (t < nb) ? bsum[t] : 0;
    sd[t] = v; __syncthreads();
    for (int off = 1; off < 256; off <<= 1) {
        int add = (t >= off) ? sd[t - off] : 0;
        __syncthreads();
        sd[t] += add;
        __syncthreads();
    }
    if (t < nb) bsum[t] = sd[t] - v;   // exclusive
}

__global__ void scan_apply(const int* __restrict__ deg, const int* __restrict__ bsum,
                           int* __restrict__ rowptr, int n, int e) {
    __shared__ int sd[256];
    int b = blockIdx.x, t = threadIdx.x;
    int base = b * 1024 + t * 4;
    int v[4]; int s = 0;
    #pragma unroll
    for (int k = 0; k < 4; ++k) { int i = base + k; v[k] = (i < n) ? deg[i] : 0; s += v[k]; }
    sd[t] = s; __syncthreads();
    int mine = s;
    for (int off = 1; off < 256; off <<= 1) {
        int add = (t >= off) ? sd[t - off] : 0;
        __syncthreads();
        sd[t] += add;
        __syncthreads();
    }
    int run = sd[t] - mine + bsum[b];
    #pragma unroll
    for (int k = 0; k < 4; ++k) {
        int i = base + k;
        if (i < n) rowptr[i] = run;
        run += v[k];
    }
    if (b == 0 && t == 0) rowptr[n] = e;
}

// R22: bucket-sort the chunk in LDS, then stream out coalesced runs per
// bucket. Kills the 9x write amplification of the old per-edge scatter
// (R8 counters: WRITE_SIZE 59 MB for 6.4 MB payload, 0.79 TB/s, 85 us).
// ebuf uses FIXED bucket regions of ESTRIDE entries; bcur2 (zero-init)
// holds per-bucket fill counts. Packed entry: src (17b) | (dst&255) << 17.
__global__ __launch_bounds__(256) void bin_edges4(const int* __restrict__ ei,
        int* __restrict__ bcur2, int* __restrict__ ebuf, int e) {
    __shared__ int cnt[NBKT];      // counts, then per-bucket cursor
    __shared__ int pref[512];      // inclusive prefix (padded)
    __shared__ int base[NBKT];     // global base per bucket
    __shared__ int sbuf[BIN_CHUNK];// 16 KB staging, bucket-sorted
    int t = threadIdx.x;
    int start = blockIdx.x * BIN_CHUNK;
    int end = start + BIN_CHUNK; if (end > e) end = e;
    int m = end - start;
    for (int b = t; b < NBKT; b += 256) cnt[b] = 0;
    __syncthreads();
    for (int i = start + t; i < end; i += 256)
        atomicAdd(&cnt[ei[e + i] >> 8], 1);
    __syncthreads();
    pref[t]       = (t < NBKT) ? cnt[t] : 0;
    pref[t + 256] = (t + 256 < NBKT) ? cnt[t + 256] : 0;
    __syncthreads();
    for (int off = 1; off < 512; off <<= 1) {
        int a0 = (t >= off) ? pref[t - off] : 0;
        int a1 = pref[t + 256 - off];          // t+256 >= off always (off<=256)
        __syncthreads();
        pref[t] += a0;
        pref[t + 256] += a1;
        __syncthreads();
    }
    for (int b = t; b < NBKT; b += 256) {
        int c = cnt[b];
        base[b] = (c > 0) ? atomicAdd(&bcur2[b], c) : 0;
        cnt[b] = 0;
    }
    __syncthreads();
    for (int i = start + t; i < end; i += 256) {
        int d = ei[e + i], s = ei[i];
        int b = d >> 8;
        int lo = (b == 0) ? 0 : pref[b - 1];
        int p = lo + atomicAdd(&cnt[b], 1);
        sbuf[p] = s | ((d & 255) << 17);
    }
    __syncthreads();
    for (int i = t; i < m; i += 256) {
        int loB = 0, hiB = NBKT - 1;           // smallest b with pref[b] > i
        while (loB < hiB) {
            int mid = (loB + hiB) >> 1;
            if (pref[mid] > i) hiB = mid; else loB = mid + 1;
        }
        int b = loB;
        int lofs = (b == 0) ? 0 : pref[b - 1];
        ebuf[b * ESTRIDE + base[b] + (i - lofs)] = sbuf[i];
    }
}

// R22: per-bucket degree histogram from ebuf (LDS atomics only, coalesced
// deg write). Replaces the 1.6M random global atomics of count_deg and the
// deg memset.
__global__ __launch_bounds__(256) void bucket_deg(const int* __restrict__ ebuf,
        const int* __restrict__ bcur2, int* __restrict__ deg, int n) {
    __shared__ int h[256];
    int b = blockIdx.x, t = threadIdx.x;
    h[t] = 0;
    __syncthreads();
    int cntb = bcur2[b];
    const int* src = ebuf + (size_t)b * ESTRIDE;
    for (int i = t; i < cntb; i += 256)
        atomicAdd(&h[(src[i] >> 17) & 255], 1);
    __syncthreads();
    int node = b * 256 + t;
    if (node < n) deg[node] = h[t];
}

// one block per bucket; LDS cursors; colarr writes confined to the bucket's
// contiguous CSR region. Entry count read from bcur2.
__global__ __launch_bounds__(256) void distribute(const int* __restrict__ ebuf,
        const int* __restrict__ bcur2,
        const int* __restrict__ rowptr, int* __restrict__ colarr, int n) {
    __shared__ int cur[256];
    int b = blockIdx.x, t = threadIdx.x;
    int n0 = b * 256;
    int n1 = n0 + 256; if (n1 > n) n1 = n;
    if (n0 + t < n1) cur[t] = rowptr[n0 + t];
    __syncthreads();
    int cntb = bcur2[b];
    const int* src = ebuf + (size_t)b * ESTRIDE;
    for (int i = t; i < cntb; i += 256) {
        int v = src[i];
        int pos = atomicAdd(&cur[(v >> 17) & 255], 1);
        colarr[pos] = v & 0x1FFFF;
    }
}

// ---------------- weight pre-split (all 8 matrices, one launch) ----------------
// MFMA B-fragment layout: lane holds B[k=(lane>>4)*8+j][n=lane&15], j=0..7.
// Storage: [(kc*8+nt)*64 + lane]*8 + j. hi=bf16(W), lo=bf16(W-hi).

__global__ void wsplit_all(
        const float* __restrict__ w0, const float* __restrict__ w1,
        const float* __restrict__ w2, const float* __restrict__ w3,
        const float* __restrict__ w4, const float* __restrict__ w5,
        const float* __restrict__ w6, const float* __restrict__ w7,
        ushort* __restrict__ hiB, ushort* __restrict__ loB) {
    const float* ws[8] = {w0, w1, w2, w3, w4, w5, w6, w7};
    int gidx = blockIdx.x * 256 + threadIdx.x;   // 0..131071
    int mi = gidx >> 14;
    int idx = gidx & 16383;
    int j = idx & 7, l = (idx >> 3) & 63, blk = idx >> 9;
    int kc = blk >> 3, nt = blk & 7;
    int k = kc * 32 + (l >> 4) * 8 + j;
    int n = nt * 16 + (l & 15);
    float f = ws[mi][k * 128 + n];
    ushort h = f2bf(f);
    float hf = __uint_as_float((uint)h << 16);
    hiB[gidx] = h;
    loB[gidx] = f2bf(f - hf);
}

// ---------------- layer-0 aggregation (d=7) ----------------

__global__ __launch_bounds__(256) void agg7(const float* __restrict__ xin,
        const int* __restrict__ rowptr, const int* __restrict__ colarr,
        float* __restrict__ h0, int n) {
    int node = blockIdx.x * 32 + (threadIdx.x >> 3);
    int f = threadIdx.x & 7;
    if (node >= n) return;
    int fidx = (f < 7) ? f : 0;
    float acc = xin[node * 7 + fidx];
    int beg = rowptr[node], end = rowptr[node + 1];
    int j = beg;
    for (; j + 4 <= end; j += 4) {
        int s0 = colarr[j], s1 = colarr[j+1], s2 = colarr[j+2], s3 = colarr[j+3];
        float v0 = xin[s0*7 + fidx], v1 = xin[s1*7 + fidx];
        float v2 = xin[s2*7 + fidx], v3 = xin[s3*7 + fidx];
        acc += (v0 + v1) + (v2 + v3);
    }
    for (; j < end; ++j) acc += xin[colarr[j]*7 + fidx];
    h0[node * 8 + f] = (f < 7) ? acc : 0.f;
}

// ------- fused MLP + JK + pool (512 thr = 8 waves, 32-row / 16 KB tile) -------
// R21: JK pooling from registers (shfl_xor(16)+shfl_xor(32), one atomic per
// column); uniform staged/fallback gather branch; INMODE 2 fuses the K=7
// first linear.

// element (r, cu) lives at bufHL[h][r][ ((cu>>3) ^ (r&7))*8 + (cu&7) ]
__device__ __forceinline__ int swch(int chunk, int r) { return chunk ^ (r & 7); }

__device__ __forceinline__ void gemm_mfma(
        const ushort* __restrict__ WH, const ushort* __restrict__ WL,
        const ushort (&bufHL)[2][32][128], int w, int lm, int lq, int l,
        f32x4 (&acc)[2])
{
    #pragma unroll
    for (int mi = 0; mi < 2; ++mi) acc[mi] = (f32x4){0.f, 0.f, 0.f, 0.f};
    const short8* BH = (const short8*)WH;
    const short8* BL = (const short8*)WL;
    #pragma unroll
    for (int kc = 0; kc < 4; ++kc) {
        short8 bh = BH[(kc * 8 + w) * 64 + l];
        short8 bl = BL[(kc * 8 + w) * 64 + l];
        #pragma unroll
        for (int mi = 0; mi < 2; ++mi) {
            int row = mi * 16 + lm;
            int ch = swch(kc * 4 + lq, row);
            short8 ah = *(const short8*)&bufHL[0][row][ch * 8];
            short8 al = *(const short8*)&bufHL[1][row][ch * 8];
            acc[mi] = __builtin_amdgcn_mfma_f32_16x16x32_bf16(ah, bh, acc[mi], 0, 0, 0);
            acc[mi] = __builtin_amdgcn_mfma_f32_16x16x32_bf16(al, bh, acc[mi], 0, 0, 0);
            acc[mi] = __builtin_amdgcn_mfma_f32_16x16x32_bf16(ah, bl, acc[mi], 0, 0, 0);
        }
    }
}

// relu + bias; write hi/lo back to LDS; optional row-major bf16 XB out
__device__ __forceinline__ void epi_store(f32x4 (&acc)[2], const float* __restrict__ bias,
        ushort (&bufHL)[2][32][128], int row0, int n, int w, int lm, int lq,
        ushort* __restrict__ xout)
{
    int col = w * 16 + lm;
    float bv = bias[col];
    #pragma unroll
    for (int mi = 0; mi < 2; ++mi) {
        #pragma unroll
        for (int rr = 0; rr < 4; ++rr) {
            int row = mi * 16 + lq * 4 + rr;
            int gr = row0 + row;
            float v = fmaxf(acc[mi][rr] + bv, 0.f);
            if (gr >= n) v = 0.f;
            ushort hi = f2bf(v);
            float hf = __uint_as_float((uint)hi << 16);
            ushort lo = f2bf(v - hf);
            int off = (swch(col >> 3, row) << 3) | (col & 7);
            bufHL[0][row][off] = hi;
            bufHL[1][row][off] = lo;
            if (xout != nullptr && gr < n)
                xout[(size_t)gr * 128 + col] = hi;
        }
    }
}

template<int INMODE, bool DO_A, bool LASTB, bool WRITE_X>
__global__ __launch_bounds__(512, 8) void mlp_fused(
        const ushort* __restrict__ in_bf,
        const float* __restrict__ h0in, const float* __restrict__ W0a,
        const float* __restrict__ b0a,
        const int* __restrict__ rowptr, const int* __restrict__ colarr,
        const ushort* __restrict__ WaH, const ushort* __restrict__ WaL,
        const float* __restrict__ ba,
        const ushort* __restrict__ WbH, const ushort* __restrict__ WbL,
        const float* __restrict__ bb,
        const ushort* __restrict__ WjH, const ushort* __restrict__ WjL,
        const float* __restrict__ bjk,
        const int* __restrict__ batch,
        ushort* __restrict__ xout_bf, float* __restrict__ pooled, int n)
{
    __shared__ __align__(16) ushort bufHL[2][32][128];   // 16 KB (hi | lo)
    __shared__ float wlds[(INMODE == 2) ? 1024 : 1];     // W0a(896) + b0a(128)
    int t = threadIdx.x;
    int row0 = blockIdx.x * 32;

    if (INMODE == 1) {
        // LDS-staged indices; 16 threads/row, 1 uint4 chunk; x4 unroll.
        int* idx_lds = (int*)&bufHL[0][0][0];      // capacity 4096 ints (16 KB)
        int rlast = row0 + 32; if (rlast > n) rlast = n;
        int eb = rowptr[row0];
        int cnt = rowptr[rlast] - eb;
        bool allstaged = (cnt <= 4096);
        int staged = allstaged ? cnt : 0;
        for (int i = t; i < staged; i += 512) idx_lds[i] = colarr[eb + i];
        __syncthreads();

        int r = t >> 4, q = t & 15;
        int gr = row0 + r;
        float f[8];
        #pragma unroll
        for (int j = 0; j < 8; ++j) f[j] = 0.f;
        if (gr < n) {
            const uint4* sp = (const uint4*)(in_bf + (size_t)gr * 128);
            uint4 v = sp[q];
            f[0] = bflo(v.x); f[1] = bfhi(v.x);
            f[2] = bflo(v.y); f[3] = bfhi(v.y);
            f[4] = bflo(v.z); f[5] = bfhi(v.z);
            f[6] = bflo(v.w); f[7] = bfhi(v.w);
            int beg = rowptr[gr] - eb, end = rowptr[gr + 1] - eb;
            if (allstaged) {
                int j = beg;
                for (; j + 4 <= end; j += 4) {
                    int s0 = idx_lds[j],     s1 = idx_lds[j + 1];
                    int s2 = idx_lds[j + 2], s3 = idx_lds[j + 3];
                    uint4 v0 = ((const uint4*)(in_bf + (size_t)s0 * 128))[q];
                    uint4 v1 = ((const uint4*)(in_bf + (size_t)s1 * 128))[q];
                    uint4 v2 = ((const uint4*)(in_bf + (size_t)s2 * 128))[q];
                    uint4 v3 = ((const uint4*)(in_bf + (size_t)s3 * 128))[q];
                    f[0] += (bflo(v0.x) + bflo(v1.x)) + (bflo(v2.x) + bflo(v3.x));
                    f[1] += (bfhi(v0.x) + bfhi(v1.x)) + (bfhi(v2.x) + bfhi(v3.x));
                    f[2] += (bflo(v0.y) + bflo(v1.y)) + (bflo(v2.y) + bflo(v3.y));
                    f[3] += (bfhi(v0.y) + bfhi(v1.y)) + (bfhi(v2.y) + bfhi(v3.y));
                    f[4] += (bflo(v0.z) + bflo(v1.z)) + (bflo(v2.z) + bflo(v3.z));
                    f[5] += (bfhi(v0.z) + bfhi(v1.z)) + (bfhi(v2.z) + bfhi(v3.z));
                    f[6] += (bflo(v0.w) + bflo(v1.w)) + (bflo(v2.w) + bflo(v3.w));
                    f[7] += (bfhi(v0.w) + bfhi(v1.w)) + (bfhi(v2.w) + bfhi(v3.w));
                }
                for (; j < end; ++j) {
                    int s0 = idx_lds[j];
                    uint4 v2 = ((const uint4*)(in_bf + (size_t)s0 * 128))[q];
                    f[0] += bflo(v2.x); f[1] += bfhi(v2.x);
                    f[2] += bflo(v2.y); f[3] += bfhi(v2.y);
                    f[4] += bflo(v2.z); f[5] += bfhi(v2.z);
                    f[6] += bflo(v2.w); f[7] += bfhi(v2.w);
                }
            } else {
                for (int j = beg; j < end; ++j) {
                    int s0 = colarr[eb + j];
                    uint4 v2 = ((const uint4*)(in_bf + (size_t)s0 * 128))[q];
                    f[0] += bflo(v2.x); f[1] += bfhi(v2.x);
                    f[2] += bflo(v2.y); f[3] += bfhi(v2.y);
                    f[4] += bflo(v2.z); f[5] += bfhi(v2.z);
                    f[6] += bflo(v2.w); f[7] += bfhi(v2.w);
                }
            }
        }
        __syncthreads();   // all idx_lds reads done before bufHL is overwritten
        {
            short8 hi8, lo8;
            #pragma unroll
            for (int j = 0; j < 8; ++j) {
                ushort h = f2bf(f[j]);
                hi8[j] = (short)h;
                float hf = __uint_as_float((uint)h << 16);
                lo8[j] = (short)f2bf(f[j] - hf);
            }
            int ch = swch(q, r);
            *(short8*)&bufHL[0][r][ch * 8] = hi8;
            *(short8*)&bufHL[1][r][ch * 8] = lo8;
        }
    } else {
        // INMODE 2: t0 = relu(h0 @ W0a + b0a), K=7, computed in-block.
        for (int l = t; l < 1024; l += 512)
            wlds[l] = (l < 896) ? W0a[l] : b0a[l - 896];
        __syncthreads();
        int r = t >> 4, cs = t & 15;          // row, 8-col chunk
        int gr = row0 + r;
        float h[7];
        #pragma unroll
        for (int k = 0; k < 7; ++k) h[k] = (gr < n) ? h0in[gr * 8 + k] : 0.f;
        float o[8];
        #pragma unroll
        for (int jj = 0; jj < 8; ++jj) {
            int c = cs * 8 + jj;
            float a = wlds[896 + c];
            #pragma unroll
            for (int k = 0; k < 7; ++k) a += h[k] * wlds[k * 128 + c];
            o[jj] = (gr < n) ? fmaxf(a, 0.f) : 0.f;
        }
        short8 hi8, lo8;
        #pragma unroll
        for (int jj = 0; jj < 8; ++jj) {
            ushort hh = f2bf(o[jj]);
            hi8[jj] = (short)hh;
            lo8[jj] = (short)f2bf(o[jj] - __uint_as_float((uint)hh << 16));
        }
        int ch = swch(cs, r);
        *(short8*)&bufHL[0][r][ch * 8] = hi8;
        *(short8*)&bufHL[1][r][ch * 8] = lo8;
    }
    __syncthreads();

    int w = t >> 6, l = t & 63;
    int lm = l & 15, lq = l >> 4;
    f32x4 acc[2];

    if (DO_A) {
        gemm_mfma(WaH, WaL, bufHL, w, lm, lq, l, acc);
        __syncthreads();
        epi_store(acc, ba, bufHL, row0, n, w, lm, lq, nullptr);
        __syncthreads();
    }

    gemm_mfma(WbH, WbL, bufHL, w, lm, lq, l, acc);
    __syncthreads();
    epi_store(acc, bb, bufHL, row0, n, w, lm, lq, WRITE_X ? xout_bf : nullptr);
    __syncthreads();

    gemm_mfma(WjH, WjL, bufHL, w, lm, lq, l, acc);
    // no LDS use after this point -> no barrier; pool from registers.

    int colj = w * 16 + lm;
    float bvj = LASTB ? bjk[colj] : 0.f;
    float jv[2][4];
    #pragma unroll
    for (int mi = 0; mi < 2; ++mi) {
        #pragma unroll
        for (int rr = 0; rr < 4; ++rr) {
            int gr = row0 + mi * 16 + lq * 4 + rr;
            jv[mi][rr] = (gr < n) ? acc[mi][rr] + bvj : 0.f;
        }
    }
    int row_last = row0 + 31; if (row_last > n - 1) row_last = n - 1;
    int g_first = batch[row0];
    int g_last  = batch[row_last];
    if (g_first == g_last) {
        float s8 = ((jv[0][0] + jv[0][1]) + (jv[0][2] + jv[0][3]))
                 + ((jv[1][0] + jv[1][1]) + (jv[1][2] + jv[1][3]));
        s8 += __shfl_xor(s8, 16);
        s8 += __shfl_xor(s8, 32);
        if (lq == 0) atomicAdd(&pooled[g_first * 128 + colj], s8);
    } else {
        #pragma unroll
        for (int mi = 0; mi < 2; ++mi) {
            int rbase = row0 + mi * 16 + lq * 4;
            int gprev = batch[(rbase <= row_last) ? rbase : row_last];
            float run = 0.f;
            #pragma unroll
            for (int rr = 0; rr < 4; ++rr) {
                int gr = rbase + rr;
                int g = batch[(gr <= row_last) ? gr : row_last];
                if (g != gprev) {
                    atomicAdd(&pooled[gprev * 128 + colj], run);
                    run = 0.f; gprev = g;
                }
                run += jv[mi][rr];
            }
            atomicAdd(&pooled[gprev * 128 + colj], run);
        }
    }
}

// ---------------- classifier ----------------

__global__ __launch_bounds__(256) void classifier(const float* __restrict__ pooled,
        const float* __restrict__ Wc1, const float* __restrict__ bc1,
        const float* __restrict__ gamma, const float* __restrict__ beta,
        const float* __restrict__ rmean, const float* __restrict__ rvar,
        const float* __restrict__ Wc2, const float* __restrict__ bc2,
        float* __restrict__ out) {
    int g = blockIdx.x, t = threadIdx.x;
    __shared__ float p[128];
    __shared__ float r0[256], r1[256];
    if (t < 128) p[t] = pooled[g * 128 + t];
    __syncthreads();
    float acc = bc1[t];
    #pragma unroll 8
    for (int k = 0; k < 128; ++k) acc += p[k] * Wc1[k * 256 + t];
    float z = (acc - rmean[t]) * rsqrtf(rvar[t] + 1e-5f) * gamma[t] + beta[t];
    z = fmaxf(z, 0.f);
    r0[t] = z * Wc2[t * 2 + 0];
    r1[t] = z * Wc2[t * 2 + 1];
    __syncthreads();
    for (int s = 128; s > 0; s >>= 1) {
        if (t < s) { r0[t] += r0[t + s]; r1[t] += r1[t + s]; }
        __syncthreads();
    }
    if (t == 0) {
        out[g * 2 + 0] = r0[0] + bc2[0];
        out[g * 2 + 1] = r1[0] + bc2[1];
    }
}

// ---------------- launch ----------------

static inline size_t al256(size_t x) { return (x + 255) & ~size_t(255); }

extern "C" void kernel_launch(void* const* d_in, const int* in_sizes, int n_in,
                              void* d_out, int out_size, void* d_ws, size_t ws_size,
                              hipStream_t stream) {
    const float* x    = (const float*)d_in[0];
    const int*   ei   = (const int*)  d_in[1];
    const int*   batch= (const int*)  d_in[3];
    const float* W0a = (const float*)d_in[4];  const float* b0a = (const float*)d_in[5];
    const float* W0b = (const float*)d_in[6];  const float* b0b = (const float*)d_in[7];
    const float* W1a = (const float*)d_in[8];  const float* b1a = (const float*)d_in[9];
    const float* W1b = (const float*)d_in[10]; const float* b1b = (const float*)d_in[11];
    const float* W2a = (const float*)d_in[12]; const float* b2a = (const float*)d_in[13];
    const float* W2b = (const float*)d_in[14]; const float* b2b = (const float*)d_in[15];
    const float* Wjk = (const float*)d_in[16]; const float* bjk = (const float*)d_in[17];
    const float* Wc1 = (const float*)d_in[18]; const float* bc1 = (const float*)d_in[19];
    const float* gamma=(const float*)d_in[20]; const float* beta= (const float*)d_in[21];
    const float* rmean=(const float*)d_in[22]; const float* rvar= (const float*)d_in[23];
    const float* Wc2 = (const float*)d_in[24]; const float* bc2 = (const float*)d_in[25];
    float* out = (float*)d_out;

    const int N = NN, E = EE, B = BB;

    char* w = (char*)d_ws;
    size_t off = 0;
    int* deg    = (int*)(w + off); off = al256(off + (size_t)N * 4);
    int* rowptr = (int*)(w + off); off = al256(off + (size_t)(N + 1) * 4);
    int* bcur2  = (int*)(w + off); off = al256(off + (size_t)NBKT * 4);
    int* colarr = (int*)(w + off); off = al256(off + (size_t)E * 4);
    int* ebuf   = (int*)(w + off); off = al256(off + (size_t)NBKT * ESTRIDE * 4);
    int* bsum   = (int*)(w + off); off = al256(off + 1024 * 4);
    float* h0   = (float*)(w + off); off = al256(off + (size_t)N * 8 * 4);
    ushort* XB1 = (ushort*)(w + off); off = al256(off + (size_t)N * 128 * 2);
    ushort* XB2 = (ushort*)(w + off); off = al256(off + (size_t)N * 128 * 2);
    float* pooled = (float*)(w + off); off = al256(off + (size_t)B * 128 * 4);
    ushort* wfH = (ushort*)(w + off); off = al256(off + (size_t)8 * 16384 * 2);
    ushort* wfL = (ushort*)(w + off); off = al256(off + (size_t)8 * 16384 * 2);

    hipMemsetAsync(bcur2, 0, (size_t)NBKT * 4, stream);
    hipMemsetAsync(pooled, 0, (size_t)B * 128 * 4, stream);

    // pre-split weights (order: W0b, W1a, W1b, W2a, W2b, Wjk0, Wjk1, Wjk2)
    wsplit_all<<<512, 256, 0, stream>>>(W0b, W1a, W1b, W2a, W2b,
                                        Wjk, Wjk + 128 * 128, Wjk + 256 * 128,
                                        wfH, wfL);

    int nb = (N + 1023) / 1024;   // 98

    bin_edges4<<<(E + BIN_CHUNK - 1) / BIN_CHUNK, 256, 0, stream>>>(ei, bcur2, ebuf, E);
    bucket_deg<<<NBKT, 256, 0, stream>>>(ebuf, bcur2, deg, N);
    scan_partial<<<nb, 256, 0, stream>>>(deg, bsum, N);
    scan_bsum<<<1, 256, 0, stream>>>(bsum, nb);
    scan_apply<<<nb, 256, 0, stream>>>(deg, bsum, rowptr, N, E);
    distribute<<<NBKT, 256, 0, stream>>>(ebuf, bcur2, rowptr, colarr, N);

    int gLin = (N + 31) / 32;   // 3125

    // Layer 0: agg7 -> mlp0 (lin7 fused in, INMODE2), x1 -> XB1 (bf16)
    agg7<<<(N + 31) / 32, 256, 0, stream>>>(x, rowptr, colarr, h0, N);
    mlp_fused<2, false, false, true><<<gLin, 512, 0, stream>>>(
        nullptr, h0, W0a, b0a, rowptr, colarr,
        nullptr, nullptr, nullptr,
        wfH + 0 * 16384, wfL + 0 * 16384, b0b,
        wfH + 5 * 16384, wfL + 5 * 16384, nullptr,
        batch, XB1, pooled, N);

    // Layer 1: bf16 gather XB1 -> MLP -> x2 -> XB2 (bf16)
    mlp_fused<1, true, false, true><<<gLin, 512, 0, stream>>>(
        XB1, nullptr, nullptr, nullptr, rowptr, colarr,
        wfH + 1 * 16384, wfL + 1 * 16384, b1a,
        wfH + 2 * 16384, wfL + 2 * 16384, b1b,
        wfH + 6 * 16384, wfL + 6 * 16384, nullptr,
        batch, XB2, pooled, N);

    // Layer 2: bf16 gather XB2 -> MLP -> jk2 (x3 never materialized)
    mlp_fused<1, true, true, false><<<gLin, 512, 0, stream>>>(
        XB2, nullptr, nullptr, nullptr, rowptr, colarr,
        wfH + 3 * 16384, wfL + 3 * 16384, b2a,
        wfH + 4 * 16384, wfL + 4 * 16384, b2b,
        wfH + 7 * 16384, wfL + 7 * 16384, bjk,
        batch, nullptr, pooled, N);

    classifier<<<B, 256, 0, stream>>>(pooled, Wc1, bc1, gamma, beta,
                                      rmean, rvar, Wc2, bc2, out);
}

// Round 10
// 377.546 us; speedup vs baseline: 1.3973x; 1.0304x over previous
//
#include <hip/hip_runtime.h>

#define NN 100000
#define EE 1600000
#define BB 256
#define IN_F 7
#define HH 128
#define NBKT 391        // ceil(NN/256) buckets for binned CSR fill
#define BIN_CHUNK 4096  // edges per bin_edges4 block
#define ESTRIDE 8192    // fixed ebuf capacity per bucket (mean 4096, sigma 64)

typedef unsigned int uint;
typedef unsigned short ushort;
typedef __attribute__((ext_vector_type(8))) short short8;
typedef __attribute__((ext_vector_type(4))) float f32x4;

// ---------------- bf16 helpers ----------------

__device__ __forceinline__ float bflo(uint u) { return __uint_as_float(u << 16); }
__device__ __forceinline__ float bfhi(uint u) { return __uint_as_float(u & 0xFFFF0000u); }
__device__ __forceinline__ ushort f2bf(float x) {   // RNE; inputs finite
    uint u = __float_as_uint(x);
    u = (u + 0x7FFFu + ((u >> 16) & 1u)) >> 16;
    return (ushort)u;
}

// ---------------- CSR build ----------------

// R22: bucket-sort the chunk in LDS, then stream out coalesced runs per
// bucket. ebuf uses FIXED bucket regions of ESTRIDE entries; bcur2
// (zero-init) holds per-bucket fill counts. Entry: src(17b) | (dst&255)<<17.
__global__ __launch_bounds__(256) void bin_edges4(const int* __restrict__ ei,
        int* __restrict__ bcur2, int* __restrict__ ebuf, int e) {
    __shared__ int cnt[NBKT];      // counts, then per-bucket cursor
    __shared__ int pref[512];      // inclusive prefix (padded)
    __shared__ int base[NBKT];     // global base per bucket
    __shared__ int sbuf[BIN_CHUNK];// 16 KB staging, bucket-sorted
    int t = threadIdx.x;
    int start = blockIdx.x * BIN_CHUNK;
    int end = start + BIN_CHUNK; if (end > e) end = e;
    int m = end - start;
    for (int b = t; b < NBKT; b += 256) cnt[b] = 0;
    __syncthreads();
    for (int i = start + t; i < end; i += 256)
        atomicAdd(&cnt[ei[e + i] >> 8], 1);
    __syncthreads();
    pref[t]       = (t < NBKT) ? cnt[t] : 0;
    pref[t + 256] = (t + 256 < NBKT) ? cnt[t + 256] : 0;
    __syncthreads();
    for (int off = 1; off < 512; off <<= 1) {
        int a0 = (t >= off) ? pref[t - off] : 0;
        int a1 = pref[t + 256 - off];          // t+256 >= off always (off<=256)
        __syncthreads();
        pref[t] += a0;
        pref[t + 256] += a1;
        __syncthreads();
    }
    for (int b = t; b < NBKT; b += 256) {
        int c = cnt[b];
        base[b] = (c > 0) ? atomicAdd(&bcur2[b], c) : 0;
        cnt[b] = 0;
    }
    __syncthreads();
    for (int i = start + t; i < end; i += 256) {
        int d = ei[e + i], s = ei[i];
        int b = d >> 8;
        int lo = (b == 0) ? 0 : pref[b - 1];
        int p = lo + atomicAdd(&cnt[b], 1);
        sbuf[p] = s | ((d & 255) << 17);
    }
    __syncthreads();
    for (int i = t; i < m; i += 256) {
        int loB = 0, hiB = NBKT - 1;           // smallest b with pref[b] > i
        while (loB < hiB) {
            int mid = (loB + hiB) >> 1;
            if (pref[mid] > i) hiB = mid; else loB = mid + 1;
        }
        int b = loB;
        int lofs = (b == 0) ? 0 : pref[b - 1];
        ebuf[b * ESTRIDE + base[b] + (i - lofs)] = sbuf[i];
    }
}

// R23: exclusive scan of the 391 bucket totals (one block).
__global__ __launch_bounds__(512) void bucket_scan(const int* __restrict__ bcur2,
        int* __restrict__ bktbase) {
    __shared__ int sd[512];
    int t = threadIdx.x;
    int v = (t < NBKT) ? bcur2[t] : 0;
    sd[t] = v; __syncthreads();
    for (int off = 1; off < 512; off <<= 1) {
        int a = (t >= off) ? sd[t - off] : 0;
        __syncthreads();
        sd[t] += a;
        __syncthreads();
    }
    if (t < NBKT) bktbase[t] = sd[t] - v;   // exclusive
}

// R23: one block per bucket. Merges bucket_deg + 3 scan kernels + distribute:
// LDS histogram over the bucket's ebuf region -> 256-wide prefix -> rowptr
// (coalesced write) -> LDS-cursor scatter into colarr. Second ebuf read is
// L2-hot (just touched by the histogram pass).
__global__ __launch_bounds__(256) void distribute2(const int* __restrict__ ebuf,
        const int* __restrict__ bcur2, const int* __restrict__ bktbase,
        int* __restrict__ rowptr, int* __restrict__ colarr, int n, int e) {
    __shared__ int h[256];
    __shared__ int pr[256];
    int b = blockIdx.x, t = threadIdx.x;
    int cntb = bcur2[b];
    int base_b = bktbase[b];
    const int* src = ebuf + (size_t)b * ESTRIDE;
    h[t] = 0;
    __syncthreads();
    for (int i = t; i < cntb; i += 256)
        atomicAdd(&h[(src[i] >> 17) & 255], 1);
    __syncthreads();
    int v = h[t];
    pr[t] = v; __syncthreads();
    for (int off = 1; off < 256; off <<= 1) {
        int a = (t >= off) ? pr[t - off] : 0;
        __syncthreads();
        pr[t] += a;
        __syncthreads();
    }
    int excl = pr[t] - v;
    int node = b * 256 + t;
    if (node <= n) rowptr[node] = base_b + excl;   // node==n -> base+cntb == e
    h[t] = base_b + excl;   // cursor
    __syncthreads();
    for (int i = t; i < cntb; i += 256) {
        int vv = src[i];
        int pos = atomicAdd(&h[(vv >> 17) & 255], 1);
        colarr[pos] = vv & 0x1FFFF;
    }
}

// ---------------- weight pre-split (all 8 matrices, one launch) ----------------
// MFMA B-fragment layout: lane holds B[k=(lane>>4)*8+j][n=lane&15], j=0..7.
// Storage: [(kc*8+nt)*64 + lane]*8 + j. hi=bf16(W), lo=bf16(W-hi).

__global__ void wsplit_all(
        const float* __restrict__ w0, const float* __restrict__ w1,
        const float* __restrict__ w2, const float* __restrict__ w3,
        const float* __restrict__ w4, const float* __restrict__ w5,
        const float* __restrict__ w6, const float* __restrict__ w7,
        ushort* __restrict__ hiB, ushort* __restrict__ loB) {
    const float* ws[8] = {w0, w1, w2, w3, w4, w5, w6, w7};
    int gidx = blockIdx.x * 256 + threadIdx.x;   // 0..131071
    int mi = gidx >> 14;
    int idx = gidx & 16383;
    int j = idx & 7, l = (idx >> 3) & 63, blk = idx >> 9;
    int kc = blk >> 3, nt = blk & 7;
    int k = kc * 32 + (l >> 4) * 8 + j;
    int n = nt * 16 + (l & 15);
    float f = ws[mi][k * 128 + n];
    ushort h = f2bf(f);
    float hf = __uint_as_float((uint)h << 16);
    hiB[gidx] = h;
    loB[gidx] = f2bf(f - hf);
}

// ------- fused MLP + JK + pool (512 thr = 8 waves, 32-row / 16 KB tile) -------
// R23: INMODE 2 additionally fuses the d=7 aggregation (agg7 kernel removed):
// 256 threads (8/row) gather x (2.8 MB, L2-resident) via idx_lds, h -> 1 KB
// LDS, then the K=7 linear as before. INMODE 1 = bf16 gather from row-major
// XB. JK pooling from registers (R21).

// element (r, cu) lives at bufHL[h][r][ ((cu>>3) ^ (r&7))*8 + (cu&7) ]
__device__ __forceinline__ int swch(int chunk, int r) { return chunk ^ (r & 7); }

__device__ __forceinline__ void gemm_mfma(
        const ushort* __restrict__ WH, const ushort* __restrict__ WL,
        const ushort (&bufHL)[2][32][128], int w, int lm, int lq, int l,
        f32x4 (&acc)[2])
{
    #pragma unroll
    for (int mi = 0; mi < 2; ++mi) acc[mi] = (f32x4){0.f, 0.f, 0.f, 0.f};
    const short8* BH = (const short8*)WH;
    const short8* BL = (const short8*)WL;
    #pragma unroll
    for (int kc = 0; kc < 4; ++kc) {
        short8 bh = BH[(kc * 8 + w) * 64 + l];
        short8 bl = BL[(kc * 8 + w) * 64 + l];
        #pragma unroll
        for (int mi = 0; mi < 2; ++mi) {
            int row = mi * 16 + lm;
            int ch = swch(kc * 4 + lq, row);
            short8 ah = *(const short8*)&bufHL[0][row][ch * 8];
            short8 al = *(const short8*)&bufHL[1][row][ch * 8];
            acc[mi] = __builtin_amdgcn_mfma_f32_16x16x32_bf16(ah, bh, acc[mi], 0, 0, 0);
            acc[mi] = __builtin_amdgcn_mfma_f32_16x16x32_bf16(al, bh, acc[mi], 0, 0, 0);
            acc[mi] = __builtin_amdgcn_mfma_f32_16x16x32_bf16(ah, bl, acc[mi], 0, 0, 0);
        }
    }
}

// relu + bias; write hi/lo back to LDS; optional row-major bf16 XB out
__device__ __forceinline__ void epi_store(f32x4 (&acc)[2], const float* __restrict__ bias,
        ushort (&bufHL)[2][32][128], int row0, int n, int w, int lm, int lq,
        ushort* __restrict__ xout)
{
    int col = w * 16 + lm;
    float bv = bias[col];
    #pragma unroll
    for (int mi = 0; mi < 2; ++mi) {
        #pragma unroll
        for (int rr = 0; rr < 4; ++rr) {
            int row = mi * 16 + lq * 4 + rr;
            int gr = row0 + row;
            float v = fmaxf(acc[mi][rr] + bv, 0.f);
            if (gr >= n) v = 0.f;
            ushort hi = f2bf(v);
            float hf = __uint_as_float((uint)hi << 16);
            ushort lo = f2bf(v - hf);
            int off = (swch(col >> 3, row) << 3) | (col & 7);
            bufHL[0][row][off] = hi;
            bufHL[1][row][off] = lo;
            if (xout != nullptr && gr < n)
                xout[(size_t)gr * 128 + col] = hi;
        }
    }
}

template<int INMODE, bool DO_A, bool LASTB, bool WRITE_X>
__global__ __launch_bounds__(512, 8) void mlp_fused(
        const ushort* __restrict__ in_bf,
        const float* __restrict__ xin, const float* __restrict__ W0a,
        const float* __restrict__ b0a,
        const int* __restrict__ rowptr, const int* __restrict__ colarr,
        const ushort* __restrict__ WaH, const ushort* __restrict__ WaL,
        const float* __restrict__ ba,
        const ushort* __restrict__ WbH, const ushort* __restrict__ WbL,
        const float* __restrict__ bb,
        const ushort* __restrict__ WjH, const ushort* __restrict__ WjL,
        const float* __restrict__ bjk,
        const int* __restrict__ batch,
        ushort* __restrict__ xout_bf, float* __restrict__ pooled, int n)
{
    __shared__ __align__(16) ushort bufHL[2][32][128];   // 16 KB (hi | lo)
    __shared__ float wlds[(INMODE == 2) ? 1024 : 1];     // W0a(896) + b0a(128)
    __shared__ float h_lds[(INMODE == 2) ? 32 : 1][8];   // 1 KB agg output
    int t = threadIdx.x;
    int row0 = blockIdx.x * 32;

    if (INMODE == 1) {
        // LDS-staged indices; 16 threads/row, 1 uint4 chunk; x4 unroll.
        int* idx_lds = (int*)&bufHL[0][0][0];      // capacity 4096 ints (16 KB)
        int rlast = row0 + 32; if (rlast > n) rlast = n;
        int eb = rowptr[row0];
        int cnt = rowptr[rlast] - eb;
        bool allstaged = (cnt <= 4096);
        int staged = allstaged ? cnt : 0;
        for (int i = t; i < staged; i += 512) idx_lds[i] = colarr[eb + i];
        __syncthreads();

        int r = t >> 4, q = t & 15;
        int gr = row0 + r;
        float f[8];
        #pragma unroll
        for (int j = 0; j < 8; ++j) f[j] = 0.f;
        if (gr < n) {
            const uint4* sp = (const uint4*)(in_bf + (size_t)gr * 128);
            uint4 v = sp[q];
            f[0] = bflo(v.x); f[1] = bfhi(v.x);
            f[2] = bflo(v.y); f[3] = bfhi(v.y);
            f[4] = bflo(v.z); f[5] = bfhi(v.z);
            f[6] = bflo(v.w); f[7] = bfhi(v.w);
            int beg = rowptr[gr] - eb, end = rowptr[gr + 1] - eb;
            if (allstaged) {
                int j = beg;
                for (; j + 4 <= end; j += 4) {
                    int s0 = idx_lds[j],     s1 = idx_lds[j + 1];
                    int s2 = idx_lds[j + 2], s3 = idx_lds[j + 3];
                    uint4 v0 = ((const uint4*)(in_bf + (size_t)s0 * 128))[q];
                    uint4 v1 = ((const uint4*)(in_bf + (size_t)s1 * 128))[q];
                    uint4 v2 = ((const uint4*)(in_bf + (size_t)s2 * 128))[q];
                    uint4 v3 = ((const uint4*)(in_bf + (size_t)s3 * 128))[q];
                    f[0] += (bflo(v0.x) + bflo(v1.x)) + (bflo(v2.x) + bflo(v3.x));
                    f[1] += (bfhi(v0.x) + bfhi(v1.x)) + (bfhi(v2.x) + bfhi(v3.x));
                    f[2] += (bflo(v0.y) + bflo(v1.y)) + (bflo(v2.y) + bflo(v3.y));
                    f[3] += (bfhi(v0.y) + bfhi(v1.y)) + (bfhi(v2.y) + bfhi(v3.y));
                    f[4] += (bflo(v0.z) + bflo(v1.z)) + (bflo(v2.z) + bflo(v3.z));
                    f[5] += (bfhi(v0.z) + bfhi(v1.z)) + (bfhi(v2.z) + bfhi(v3.z));
                    f[6] += (bflo(v0.w) + bflo(v1.w)) + (bflo(v2.w) + bflo(v3.w));
                    f[7] += (bfhi(v0.w) + bfhi(v1.w)) + (bfhi(v2.w) + bfhi(v3.w));
                }
                for (; j < end; ++j) {
                    int s0 = idx_lds[j];
                    uint4 v2 = ((const uint4*)(in_bf + (size_t)s0 * 128))[q];
                    f[0] += bflo(v2.x); f[1] += bfhi(v2.x);
                    f[2] += bflo(v2.y); f[3] += bfhi(v2.y);
                    f[4] += bflo(v2.z); f[5] += bfhi(v2.z);
                    f[6] += bflo(v2.w); f[7] += bfhi(v2.w);
                }
            } else {
                for (int j = beg; j < end; ++j) {
                    int s0 = colarr[eb + j];
                    uint4 v2 = ((const uint4*)(in_bf + (size_t)s0 * 128))[q];
                    f[0] += bflo(v2.x); f[1] += bfhi(v2.x);
                    f[2] += bflo(v2.y); f[3] += bfhi(v2.y);
                    f[4] += bflo(v2.z); f[5] += bfhi(v2.z);
                    f[6] += bflo(v2.w); f[7] += bfhi(v2.w);
                }
            }
        }
        __syncthreads();   // all idx_lds reads done before bufHL is overwritten
        {
            short8 hi8, lo8;
            #pragma unroll
            for (int j = 0; j < 8; ++j) {
                ushort h = f2bf(f[j]);
                hi8[j] = (short)h;
                float hf = __uint_as_float((uint)h << 16);
                lo8[j] = (short)f2bf(f[j] - hf);
            }
            int ch = swch(q, r);
            *(short8*)&bufHL[0][r][ch * 8] = hi8;
            *(short8*)&bufHL[1][r][ch * 8] = lo8;
        }
    } else {
        // INMODE 2: fused d=7 aggregation + t0 = relu(h @ W0a + b0a).
        int* idx_lds = (int*)&bufHL[0][0][0];      // capacity 4096 ints
        int rlast = row0 + 32; if (rlast > n) rlast = n;
        int eb = rowptr[row0];
        int cnt = rowptr[rlast] - eb;
        bool allstaged = (cnt <= 4096);
        int staged = allstaged ? cnt : 0;
        for (int i = t; i < staged; i += 512) idx_lds[i] = colarr[eb + i];
        for (int l = t; l < 1024; l += 512)
            wlds[l] = (l < 896) ? W0a[l] : b0a[l - 896];
        __syncthreads();
        if (t < 256) {
            int r = t >> 3, f = t & 7;
            int fidx = (f < 7) ? f : 0;
            int gr = row0 + r;
            float acc = 0.f;
            if (gr < n) {
                acc = xin[gr * 7 + fidx];
                int beg = rowptr[gr] - eb, end = rowptr[gr + 1] - eb;
                if (allstaged) {
                    int j = beg;
                    for (; j + 4 <= end; j += 4) {
                        float a0 = xin[idx_lds[j] * 7 + fidx];
                        float a1 = xin[idx_lds[j + 1] * 7 + fidx];
                        float a2 = xin[idx_lds[j + 2] * 7 + fidx];
                        float a3 = xin[idx_lds[j + 3] * 7 + fidx];
                        acc += (a0 + a1) + (a2 + a3);
                    }
                    for (; j < end; ++j) acc += xin[idx_lds[j] * 7 + fidx];
                } else {
                    for (int j = beg; j < end; ++j)
                        acc += xin[colarr[eb + j] * 7 + fidx];
                }
            }
            h_lds[r][f] = (f < 7) ? acc : 0.f;
        }
        __syncthreads();
        int r = t >> 4, cs = t & 15;          // row, 8-col chunk
        int gr = row0 + r;
        float h[7];
        #pragma unroll
        for (int k = 0; k < 7; ++k) h[k] = h_lds[r][k];
        float o[8];
        #pragma unroll
        for (int jj = 0; jj < 8; ++jj) {
            int c = cs * 8 + jj;
            float a = wlds[896 + c];
            #pragma unroll
            for (int k = 0; k < 7; ++k) a += h[k] * wlds[k * 128 + c];
            o[jj] = (gr < n) ? fmaxf(a, 0.f) : 0.f;
        }
        __syncthreads();   // all idx_lds reads done before bufHL is overwritten
        short8 hi8, lo8;
        #pragma unroll
        for (int jj = 0; jj < 8; ++jj) {
            ushort hh = f2bf(o[jj]);
            hi8[jj] = (short)hh;
            lo8[jj] = (short)f2bf(o[jj] - __uint_as_float((uint)hh << 16));
        }
        int ch = swch(cs, r);
        *(short8*)&bufHL[0][r][ch * 8] = hi8;
        *(short8*)&bufHL[1][r][ch * 8] = lo8;
    }
    __syncthreads();

    int w = t >> 6, l = t & 63;
    int lm = l & 15, lq = l >> 4;
    f32x4 acc[2];

    if (DO_A) {
        gemm_mfma(WaH, WaL, bufHL, w, lm, lq, l, acc);
        __syncthreads();
        epi_store(acc, ba, bufHL, row0, n, w, lm, lq, nullptr);
        __syncthreads();
    }

    gemm_mfma(WbH, WbL, bufHL, w, lm, lq, l, acc);
    __syncthreads();
    epi_store(acc, bb, bufHL, row0, n, w, lm, lq, WRITE_X ? xout_bf : nullptr);
    __syncthreads();

    gemm_mfma(WjH, WjL, bufHL, w, lm, lq, l, acc);
    // no LDS use after this point -> no barrier; pool from registers.

    int colj = w * 16 + lm;
    float bvj = LASTB ? bjk[colj] : 0.f;
    float jv[2][4];
    #pragma unroll
    for (int mi = 0; mi < 2; ++mi) {
        #pragma unroll
        for (int rr = 0; rr < 4; ++rr) {
            int gr = row0 + mi * 16 + lq * 4 + rr;
            jv[mi][rr] = (gr < n) ? acc[mi][rr] + bvj : 0.f;
        }
    }
    int row_last = row0 + 31; if (row_last > n - 1) row_last = n - 1;
    int g_first = batch[row0];
    int g_last  = batch[row_last];
    if (g_first == g_last) {
        float s8 = ((jv[0][0] + jv[0][1]) + (jv[0][2] + jv[0][3]))
                 + ((jv[1][0] + jv[1][1]) + (jv[1][2] + jv[1][3]));
        s8 += __shfl_xor(s8, 16);
        s8 += __shfl_xor(s8, 32);
        if (lq == 0) atomicAdd(&pooled[g_first * 128 + colj], s8);
    } else {
        #pragma unroll
        for (int mi = 0; mi < 2; ++mi) {
            int rbase = row0 + mi * 16 + lq * 4;
            int gprev = batch[(rbase <= row_last) ? rbase : row_last];
            float run = 0.f;
            #pragma unroll
            for (int rr = 0; rr < 4; ++rr) {
                int gr = rbase + rr;
                int g = batch[(gr <= row_last) ? gr : row_last];
                if (g != gprev) {
                    atomicAdd(&pooled[gprev * 128 + colj], run);
                    run = 0.f; gprev = g;
                }
                run += jv[mi][rr];
            }
            atomicAdd(&pooled[gprev * 128 + colj], run);
        }
    }
}

// ---------------- classifier ----------------

__global__ __launch_bounds__(256) void classifier(const float* __restrict__ pooled,
        const float* __restrict__ Wc1, const float* __restrict__ bc1,
        const float* __restrict__ gamma, const float* __restrict__ beta,
        const float* __restrict__ rmean, const float* __restrict__ rvar,
        const float* __restrict__ Wc2, const float* __restrict__ bc2,
        float* __restrict__ out) {
    int g = blockIdx.x, t = threadIdx.x;
    __shared__ float p[128];
    __shared__ float r0[256], r1[256];
    if (t < 128) p[t] = pooled[g * 128 + t];
    __syncthreads();
    float acc = bc1[t];
    #pragma unroll 8
    for (int k = 0; k < 128; ++k) acc += p[k] * Wc1[k * 256 + t];
    float z = (acc - rmean[t]) * rsqrtf(rvar[t] + 1e-5f) * gamma[t] + beta[t];
    z = fmaxf(z, 0.f);
    r0[t] = z * Wc2[t * 2 + 0];
    r1[t] = z * Wc2[t * 2 + 1];
    __syncthreads();
    for (int s = 128; s > 0; s >>= 1) {
        if (t < s) { r0[t] += r0[t + s]; r1[t] += r1[t + s]; }
        __syncthreads();
    }
    if (t == 0) {
        out[g * 2 + 0] = r0[0] + bc2[0];
        out[g * 2 + 1] = r1[0] + bc2[1];
    }
}

// ---------------- launch ----------------

static inline size_t al256(size_t x) { return (x + 255) & ~size_t(255); }

extern "C" void kernel_launch(void* const* d_in, const int* in_sizes, int n_in,
                              void* d_out, int out_size, void* d_ws, size_t ws_size,
                              hipStream_t stream) {
    const float* x    = (const float*)d_in[0];
    const int*   ei   = (const int*)  d_in[1];
    const int*   batch= (const int*)  d_in[3];
    const float* W0a = (const float*)d_in[4];  const float* b0a = (const float*)d_in[5];
    const float* W0b = (const float*)d_in[6];  const float* b0b = (const float*)d_in[7];
    const float* W1a = (const float*)d_in[8];  const float* b1a = (const float*)d_in[9];
    const float* W1b = (const float*)d_in[10]; const float* b1b = (const float*)d_in[11];
    const float* W2a = (const float*)d_in[12]; const float* b2a = (const float*)d_in[13];
    const float* W2b = (const float*)d_in[14]; const float* b2b = (const float*)d_in[15];
    const float* Wjk = (const float*)d_in[16]; const float* bjk = (const float*)d_in[17];
    const float* Wc1 = (const float*)d_in[18]; const float* bc1 = (const float*)d_in[19];
    const float* gamma=(const float*)d_in[20]; const float* beta= (const float*)d_in[21];
    const float* rmean=(const float*)d_in[22]; const float* rvar= (const float*)d_in[23];
    const float* Wc2 = (const float*)d_in[24]; const float* bc2 = (const float*)d_in[25];
    float* out = (float*)d_out;

    const int N = NN, E = EE, B = BB;

    char* w = (char*)d_ws;
    size_t off = 0;
    int* rowptr = (int*)(w + off); off = al256(off + (size_t)(N + 1) * 4);
    int* bcur2  = (int*)(w + off); off = al256(off + (size_t)NBKT * 4);
    int* bktbase= (int*)(w + off); off = al256(off + (size_t)NBKT * 4);
    int* colarr = (int*)(w + off); off = al256(off + (size_t)E * 4);
    int* ebuf   = (int*)(w + off); off = al256(off + (size_t)NBKT * ESTRIDE * 4);
    ushort* XB1 = (ushort*)(w + off); off = al256(off + (size_t)N * 128 * 2);
    ushort* XB2 = (ushort*)(w + off); off = al256(off + (size_t)N * 128 * 2);
    float* pooled = (float*)(w + off); off = al256(off + (size_t)B * 128 * 4);
    ushort* wfH = (ushort*)(w + off); off = al256(off + (size_t)8 * 16384 * 2);
    ushort* wfL = (ushort*)(w + off); off = al256(off + (size_t)8 * 16384 * 2);

    hipMemsetAsync(bcur2, 0, (size_t)NBKT * 4, stream);
    hipMemsetAsync(pooled, 0, (size_t)B * 128 * 4, stream);

    // pre-split weights (order: W0b, W1a, W1b, W2a, W2b, Wjk0, Wjk1, Wjk2)
    wsplit_all<<<512, 256, 0, stream>>>(W0b, W1a, W1b, W2a, W2b,
                                        Wjk, Wjk + 128 * 128, Wjk + 256 * 128,
                                        wfH, wfL);

    bin_edges4<<<(E + BIN_CHUNK - 1) / BIN_CHUNK, 256, 0, stream>>>(ei, bcur2, ebuf, E);
    bucket_scan<<<1, 512, 0, stream>>>(bcur2, bktbase);
    distribute2<<<NBKT, 256, 0, stream>>>(ebuf, bcur2, bktbase, rowptr, colarr, N, E);

    int gLin = (N + 31) / 32;   // 3125

    // Layer 0: mlp0 (agg7 + lin7 fused in, INMODE2), x1 -> XB1 (bf16)
    mlp_fused<2, false, false, true><<<gLin, 512, 0, stream>>>(
        nullptr, x, W0a, b0a, rowptr, colarr,
        nullptr, nullptr, nullptr,
        wfH + 0 * 16384, wfL + 0 * 16384, b0b,
        wfH + 5 * 16384, wfL + 5 * 16384, nullptr,
        batch, XB1, pooled, N);

    // Layer 1: bf16 gather XB1 -> MLP -> x2 -> XB2 (bf16)
    mlp_fused<1, true, false, true><<<gLin, 512, 0, stream>>>(
        XB1, nullptr, nullptr, nullptr, rowptr, colarr,
        wfH + 1 * 16384, wfL + 1 * 16384, b1a,
        wfH + 2 * 16384, wfL + 2 * 16384, b1b,
        wfH + 6 * 16384, wfL + 6 * 16384, nullptr,
        batch, XB2, pooled, N);

    // Layer 2: bf16 gather XB2 -> MLP -> jk2 (x3 never materialized)
    mlp_fused<1, true, true, false><<<gLin, 512, 0, stream>>>(
        XB2, nullptr, nullptr, nullptr, rowptr, colarr,
        wfH + 3 * 16384, wfL + 3 * 16384, b2a,
        wfH + 4 * 16384, wfL + 4 * 16384, b2b,
        wfH + 7 * 16384, wfL + 7 * 16384, bjk,
        batch, nullptr, pooled, N);

    classifier<<<B, 256, 0, stream>>>(pooled, Wc1, bc1, gamma, beta,
                                      rmean, rvar, Wc2, bc2, out);
}

// Round 11
// 372.115 us; speedup vs baseline: 1.4177x; 1.0146x over previous
//
#include <hip/hip_runtime.h>

#define NN 100000
#define EE 1600000
#define BB 256
#define IN_F 7
#define HH 128
#define NBKT 391        // ceil(NN/256) buckets for binned CSR fill
#define BIN_CHUNK 4096  // edges per bin_edges4 block
#define ESTRIDE 8192    // fixed ebuf capacity per bucket (mean 4096, sigma 64)

typedef unsigned int uint;
typedef unsigned short ushort;
typedef __attribute__((ext_vector_type(8))) short short8;
typedef __attribute__((ext_vector_type(4))) float f32x4;

// ---------------- bf16 helpers ----------------

__device__ __forceinline__ float bflo(uint u) { return __uint_as_float(u << 16); }
__device__ __forceinline__ float bfhi(uint u) { return __uint_as_float(u & 0xFFFF0000u); }
__device__ __forceinline__ ushort f2bf(float x) {   // RNE; inputs finite
    uint u = __float_as_uint(x);
    u = (u + 0x7FFFu + ((u >> 16) & 1u)) >> 16;
    return (ushort)u;
}

// accumulate 8 bf16 (one uint4) into f[O..O+7]
#define ACC8(F, O, V) \
    F[(O)+0] += bflo((V).x); F[(O)+1] += bfhi((V).x); \
    F[(O)+2] += bflo((V).y); F[(O)+3] += bfhi((V).y); \
    F[(O)+4] += bflo((V).z); F[(O)+5] += bfhi((V).z); \
    F[(O)+6] += bflo((V).w); F[(O)+7] += bfhi((V).w);

// ---------------- CSR build ----------------

// R22: bucket-sort the chunk in LDS, then stream out coalesced runs per
// bucket. ebuf uses FIXED bucket regions of ESTRIDE entries; bcur2
// (zero-init) holds per-bucket fill counts. Entry: src(17b) | (dst&255)<<17.
__global__ __launch_bounds__(256) void bin_edges4(const int* __restrict__ ei,
        int* __restrict__ bcur2, int* __restrict__ ebuf, int e) {
    __shared__ int cnt[NBKT];      // counts, then per-bucket cursor
    __shared__ int pref[512];      // inclusive prefix (padded)
    __shared__ int base[NBKT];     // global base per bucket
    __shared__ int sbuf[BIN_CHUNK];// 16 KB staging, bucket-sorted
    int t = threadIdx.x;
    int start = blockIdx.x * BIN_CHUNK;
    int end = start + BIN_CHUNK; if (end > e) end = e;
    int m = end - start;
    for (int b = t; b < NBKT; b += 256) cnt[b] = 0;
    __syncthreads();
    for (int i = start + t; i < end; i += 256)
        atomicAdd(&cnt[ei[e + i] >> 8], 1);
    __syncthreads();
    pref[t]       = (t < NBKT) ? cnt[t] : 0;
    pref[t + 256] = (t + 256 < NBKT) ? cnt[t + 256] : 0;
    __syncthreads();
    for (int off = 1; off < 512; off <<= 1) {
        int a0 = (t >= off) ? pref[t - off] : 0;
        int a1 = pref[t + 256 - off];          // t+256 >= off always (off<=256)
        __syncthreads();
        pref[t] += a0;
        pref[t + 256] += a1;
        __syncthreads();
    }
    for (int b = t; b < NBKT; b += 256) {
        int c = cnt[b];
        base[b] = (c > 0) ? atomicAdd(&bcur2[b], c) : 0;
        cnt[b] = 0;
    }
    __syncthreads();
    for (int i = start + t; i < end; i += 256) {
        int d = ei[e + i], s = ei[i];
        int b = d >> 8;
        int lo = (b == 0) ? 0 : pref[b - 1];
        int p = lo + atomicAdd(&cnt[b], 1);
        sbuf[p] = s | ((d & 255) << 17);
    }
    __syncthreads();
    for (int i = t; i < m; i += 256) {
        int loB = 0, hiB = NBKT - 1;           // smallest b with pref[b] > i
        while (loB < hiB) {
            int mid = (loB + hiB) >> 1;
            if (pref[mid] > i) hiB = mid; else loB = mid + 1;
        }
        int b = loB;
        int lofs = (b == 0) ? 0 : pref[b - 1];
        ebuf[b * ESTRIDE + base[b] + (i - lofs)] = sbuf[i];
    }
}

// R23: exclusive scan of the 391 bucket totals (one block).
__global__ __launch_bounds__(512) void bucket_scan(const int* __restrict__ bcur2,
        int* __restrict__ bktbase) {
    __shared__ int sd[512];
    int t = threadIdx.x;
    int v = (t < NBKT) ? bcur2[t] : 0;
    sd[t] = v; __syncthreads();
    for (int off = 1; off < 512; off <<= 1) {
        int a = (t >= off) ? sd[t - off] : 0;
        __syncthreads();
        sd[t] += a;
        __syncthreads();
    }
    if (t < NBKT) bktbase[t] = sd[t] - v;   // exclusive
}

// R23: one block per bucket. LDS histogram -> 256-wide prefix -> rowptr
// (coalesced) -> LDS-cursor scatter into colarr. Second ebuf read L2-hot.
__global__ __launch_bounds__(256) void distribute2(const int* __restrict__ ebuf,
        const int* __restrict__ bcur2, const int* __restrict__ bktbase,
        int* __restrict__ rowptr, int* __restrict__ colarr, int n, int e) {
    __shared__ int h[256];
    __shared__ int pr[256];
    int b = blockIdx.x, t = threadIdx.x;
    int cntb = bcur2[b];
    int base_b = bktbase[b];
    const int* src = ebuf + (size_t)b * ESTRIDE;
    h[t] = 0;
    __syncthreads();
    for (int i = t; i < cntb; i += 256)
        atomicAdd(&h[(src[i] >> 17) & 255], 1);
    __syncthreads();
    int v = h[t];
    pr[t] = v; __syncthreads();
    for (int off = 1; off < 256; off <<= 1) {
        int a = (t >= off) ? pr[t - off] : 0;
        __syncthreads();
        pr[t] += a;
        __syncthreads();
    }
    int excl = pr[t] - v;
    int node = b * 256 + t;
    if (node <= n) rowptr[node] = base_b + excl;   // node==n -> base+cntb == e
    h[t] = base_b + excl;   // cursor
    __syncthreads();
    for (int i = t; i < cntb; i += 256) {
        int vv = src[i];
        int pos = atomicAdd(&h[(vv >> 17) & 255], 1);
        colarr[pos] = vv & 0x1FFFF;
    }
}

// ---------------- weight pre-split (all 8 matrices, one launch) ----------------
// MFMA B-fragment layout: lane holds B[k=(lane>>4)*8+j][n=lane&15], j=0..7.
// Storage: [(kc*8+nt)*64 + lane]*8 + j. hi=bf16(W), lo=bf16(W-hi).

__global__ void wsplit_all(
        const float* __restrict__ w0, const float* __restrict__ w1,
        const float* __restrict__ w2, const float* __restrict__ w3,
        const float* __restrict__ w4, const float* __restrict__ w5,
        const float* __restrict__ w6, const float* __restrict__ w7,
        ushort* __restrict__ hiB, ushort* __restrict__ loB) {
    const float* ws[8] = {w0, w1, w2, w3, w4, w5, w6, w7};
    int gidx = blockIdx.x * 256 + threadIdx.x;   // 0..131071
    int mi = gidx >> 14;
    int idx = gidx & 16383;
    int j = idx & 7, l = (idx >> 3) & 63, blk = idx >> 9;
    int kc = blk >> 3, nt = blk & 7;
    int k = kc * 32 + (l >> 4) * 8 + j;
    int n = nt * 16 + (l & 15);
    float f = ws[mi][k * 128 + n];
    ushort h = f2bf(f);
    float hf = __uint_as_float((uint)h << 16);
    hiB[gidx] = h;
    loB[gidx] = f2bf(f - hf);
}

// ------- fused MLP + JK + pool (512 thr = 8 waves, 32-row / 16 KB tile) -------
// R24: both gather paths split neighbors across 2 thread-halves to halve the
// serial chain. INMODE 1: 32 rows x 8 col-groups x 2 halves, f[16]/thread
// (32B of the row), partner combine via shfl_xor(8). INMODE 2: 512 threads
// (32 x 8 x 2) on the d=7 agg, combined through hl2. JK pooling from
// registers (R21); INMODE 2 fuses the K=7 first linear.

// element (r, cu) lives at bufHL[h][r][ ((cu>>3) ^ (r&7))*8 + (cu&7) ]
__device__ __forceinline__ int swch(int chunk, int r) { return chunk ^ (r & 7); }

__device__ __forceinline__ void gemm_mfma(
        const ushort* __restrict__ WH, const ushort* __restrict__ WL,
        const ushort (&bufHL)[2][32][128], int w, int lm, int lq, int l,
        f32x4 (&acc)[2])
{
    #pragma unroll
    for (int mi = 0; mi < 2; ++mi) acc[mi] = (f32x4){0.f, 0.f, 0.f, 0.f};
    const short8* BH = (const short8*)WH;
    const short8* BL = (const short8*)WL;
    #pragma unroll
    for (int kc = 0; kc < 4; ++kc) {
        short8 bh = BH[(kc * 8 + w) * 64 + l];
        short8 bl = BL[(kc * 8 + w) * 64 + l];
        #pragma unroll
        for (int mi = 0; mi < 2; ++mi) {
            int row = mi * 16 + lm;
            int ch = swch(kc * 4 + lq, row);
            short8 ah = *(const short8*)&bufHL[0][row][ch * 8];
            short8 al = *(const short8*)&bufHL[1][row][ch * 8];
            acc[mi] = __builtin_amdgcn_mfma_f32_16x16x32_bf16(ah, bh, acc[mi], 0, 0, 0);
            acc[mi] = __builtin_amdgcn_mfma_f32_16x16x32_bf16(al, bh, acc[mi], 0, 0, 0);
            acc[mi] = __builtin_amdgcn_mfma_f32_16x16x32_bf16(ah, bl, acc[mi], 0, 0, 0);
        }
    }
}

// relu + bias; write hi/lo back to LDS; optional row-major bf16 XB out
__device__ __forceinline__ void epi_store(f32x4 (&acc)[2], const float* __restrict__ bias,
        ushort (&bufHL)[2][32][128], int row0, int n, int w, int lm, int lq,
        ushort* __restrict__ xout)
{
    int col = w * 16 + lm;
    float bv = bias[col];
    #pragma unroll
    for (int mi = 0; mi < 2; ++mi) {
        #pragma unroll
        for (int rr = 0; rr < 4; ++rr) {
            int row = mi * 16 + lq * 4 + rr;
            int gr = row0 + row;
            float v = fmaxf(acc[mi][rr] + bv, 0.f);
            if (gr >= n) v = 0.f;
            ushort hi = f2bf(v);
            float hf = __uint_as_float((uint)hi << 16);
            ushort lo = f2bf(v - hf);
            int off = (swch(col >> 3, row) << 3) | (col & 7);
            bufHL[0][row][off] = hi;
            bufHL[1][row][off] = lo;
            if (xout != nullptr && gr < n)
                xout[(size_t)gr * 128 + col] = hi;
        }
    }
}

template<int INMODE, bool DO_A, bool LASTB, bool WRITE_X>
__global__ __launch_bounds__(512, 8) void mlp_fused(
        const ushort* __restrict__ in_bf,
        const float* __restrict__ xin, const float* __restrict__ W0a,
        const float* __restrict__ b0a,
        const int* __restrict__ rowptr, const int* __restrict__ colarr,
        const ushort* __restrict__ WaH, const ushort* __restrict__ WaL,
        const float* __restrict__ ba,
        const ushort* __restrict__ WbH, const ushort* __restrict__ WbL,
        const float* __restrict__ bb,
        const ushort* __restrict__ WjH, const ushort* __restrict__ WjL,
        const float* __restrict__ bjk,
        const int* __restrict__ batch,
        ushort* __restrict__ xout_bf, float* __restrict__ pooled, int n)
{
    __shared__ __align__(16) ushort bufHL[2][32][128];   // 16 KB (hi | lo)
    __shared__ float wlds[(INMODE == 2) ? 1024 : 1];     // W0a(896) + b0a(128)
    __shared__ float hl2[(INMODE == 2) ? 32 : 1][2][8];  // 2 KB agg halves
    int t = threadIdx.x;
    int row0 = blockIdx.x * 32;

    if (INMODE == 1) {
        // R24: 16 threads/row = 8 col-groups x 2 neighbor-halves; each thread
        // covers 32B (f[16]) of the row and walks every other neighbor; the
        // partner (t^8, same wave) holds the other half -> shfl_xor combine.
        int* idx_lds = (int*)&bufHL[0][0][0];      // capacity 4096 ints (16 KB)
        int rlast = row0 + 32; if (rlast > n) rlast = n;
        int eb = rowptr[row0];
        int cnt = rowptr[rlast] - eb;
        bool allstaged = (cnt <= 4096);
        int staged = allstaged ? cnt : 0;
        for (int i = t; i < staged; i += 512) idx_lds[i] = colarr[eb + i];
        __syncthreads();

        int r = t >> 4, sub = t & 15;
        int q8 = sub & 7, half = sub >> 3;
        int gr = row0 + r;
        float f[16];
        #pragma unroll
        for (int j = 0; j < 16; ++j) f[j] = 0.f;
        if (gr < n) {
            const uint4* sp = (const uint4*)(in_bf + (size_t)gr * 128);
            if (half == 0) {
                uint4 v0 = sp[2 * q8], v1 = sp[2 * q8 + 1];
                ACC8(f, 0, v0); ACC8(f, 8, v1);
            }
            int beg = rowptr[gr] - eb, end = rowptr[gr + 1] - eb;
            if (allstaged) {
                int j = beg + half;
                for (; j + 3 <= end; j += 4) {         // neighbors j, j+2
                    int s0 = idx_lds[j], s1 = idx_lds[j + 2];
                    const uint4* n0 = (const uint4*)(in_bf + (size_t)s0 * 128);
                    const uint4* n1 = (const uint4*)(in_bf + (size_t)s1 * 128);
                    uint4 a0 = n0[2 * q8], a1 = n0[2 * q8 + 1];
                    uint4 b0 = n1[2 * q8], b1 = n1[2 * q8 + 1];
                    ACC8(f, 0, a0); ACC8(f, 8, a1);
                    ACC8(f, 0, b0); ACC8(f, 8, b1);
                }
                for (; j < end; j += 2) {
                    int s0 = idx_lds[j];
                    const uint4* n0 = (const uint4*)(in_bf + (size_t)s0 * 128);
                    uint4 a0 = n0[2 * q8], a1 = n0[2 * q8 + 1];
                    ACC8(f, 0, a0); ACC8(f, 8, a1);
                }
            } else {
                for (int j = beg + half; j < end; j += 2) {
                    int s0 = colarr[eb + j];
                    const uint4* n0 = (const uint4*)(in_bf + (size_t)s0 * 128);
                    uint4 a0 = n0[2 * q8], a1 = n0[2 * q8 + 1];
                    ACC8(f, 0, a0); ACC8(f, 8, a1);
                }
            }
        }
        __syncthreads();   // all idx_lds reads done before bufHL is overwritten
        #pragma unroll
        for (int i = 0; i < 16; ++i) f[i] += __shfl_xor(f[i], 8);
        if (half == 0) {
            #pragma unroll
            for (int c2 = 0; c2 < 2; ++c2) {
                short8 hi8, lo8;
                #pragma unroll
                for (int j = 0; j < 8; ++j) {
                    float v = f[c2 * 8 + j];
                    ushort h = f2bf(v);
                    hi8[j] = (short)h;
                    lo8[j] = (short)f2bf(v - __uint_as_float((uint)h << 16));
                }
                int ch = swch(2 * q8 + c2, r);
                *(short8*)&bufHL[0][r][ch * 8] = hi8;
                *(short8*)&bufHL[1][r][ch * 8] = lo8;
            }
        }
    } else {
        // INMODE 2: fused d=7 aggregation (2 neighbor-halves, all 512 thr)
        // + t0 = relu(h @ W0a + b0a).
        int* idx_lds = (int*)&bufHL[0][0][0];      // capacity 4096 ints
        int rlast = row0 + 32; if (rlast > n) rlast = n;
        int eb = rowptr[row0];
        int cnt = rowptr[rlast] - eb;
        bool allstaged = (cnt <= 4096);
        int staged = allstaged ? cnt : 0;
        for (int i = t; i < staged; i += 512) idx_lds[i] = colarr[eb + i];
        for (int l = t; l < 1024; l += 512)
            wlds[l] = (l < 896) ? W0a[l] : b0a[l - 896];
        __syncthreads();
        {
            int r = t >> 4, sub = t & 15, f8 = sub & 7, half = sub >> 3;
            int fidx = (f8 < 7) ? f8 : 0;
            int gr = row0 + r;
            float acc = 0.f;
            if (gr < n) {
                if (half == 0) acc = xin[gr * 7 + fidx];
                int beg = rowptr[gr] - eb, end = rowptr[gr + 1] - eb;
                if (allstaged) {
                    int j = beg + half;
                    for (; j + 7 <= end; j += 8) {     // neighbors j,j+2,j+4,j+6
                        float a0 = xin[idx_lds[j] * 7 + fidx];
                        float a1 = xin[idx_lds[j + 2] * 7 + fidx];
                        float a2 = xin[idx_lds[j + 4] * 7 + fidx];
                        float a3 = xin[idx_lds[j + 6] * 7 + fidx];
                        acc += (a0 + a1) + (a2 + a3);
                    }
                    for (; j < end; j += 2) acc += xin[idx_lds[j] * 7 + fidx];
                } else {
                    for (int j = beg + half; j < end; j += 2)
                        acc += xin[colarr[eb + j] * 7 + fidx];
                }
            }
            hl2[r][half][f8] = (f8 < 7) ? acc : 0.f;
        }
        __syncthreads();   // agg done; idx_lds reads complete
        int r = t >> 4, cs = t & 15;          // row, 8-col chunk
        int gr = row0 + r;
        float h[7];
        #pragma unroll
        for (int k = 0; k < 7; ++k) h[k] = hl2[r][0][k] + hl2[r][1][k];
        float o[8];
        #pragma unroll
        for (int jj = 0; jj < 8; ++jj) {
            int c = cs * 8 + jj;
            float a = wlds[896 + c];
            #pragma unroll
            for (int k = 0; k < 7; ++k) a += h[k] * wlds[k * 128 + c];
            o[jj] = (gr < n) ? fmaxf(a, 0.f) : 0.f;
        }
        short8 hi8, lo8;
        #pragma unroll
        for (int jj = 0; jj < 8; ++jj) {
            ushort hh = f2bf(o[jj]);
            hi8[jj] = (short)hh;
            lo8[jj] = (short)f2bf(o[jj] - __uint_as_float((uint)hh << 16));
        }
        int ch = swch(cs, r);
        *(short8*)&bufHL[0][r][ch * 8] = hi8;
        *(short8*)&bufHL[1][r][ch * 8] = lo8;
    }
    __syncthreads();

    int w = t >> 6, l = t & 63;
    int lm = l & 15, lq = l >> 4;
    f32x4 acc[2];

    if (DO_A) {
        gemm_mfma(WaH, WaL, bufHL, w, lm, lq, l, acc);
        __syncthreads();
        epi_store(acc, ba, bufHL, row0, n, w, lm, lq, nullptr);
        __syncthreads();
    }

    gemm_mfma(WbH, WbL, bufHL, w, lm, lq, l, acc);
    __syncthreads();
    epi_store(acc, bb, bufHL, row0, n, w, lm, lq, WRITE_X ? xout_bf : nullptr);
    __syncthreads();

    gemm_mfma(WjH, WjL, bufHL, w, lm, lq, l, acc);
    // no LDS use after this point -> no barrier; pool from registers.

    int colj = w * 16 + lm;
    float bvj = LASTB ? bjk[colj] : 0.f;
    float jv[2][4];
    #pragma unroll
    for (int mi = 0; mi < 2; ++mi) {
        #pragma unroll
        for (int rr = 0; rr < 4; ++rr) {
            int gr = row0 + mi * 16 + lq * 4 + rr;
            jv[mi][rr] = (gr < n) ? acc[mi][rr] + bvj : 0.f;
        }
    }
    int row_last = row0 + 31; if (row_last > n - 1) row_last = n - 1;
    int g_first = batch[row0];
    int g_last  = batch[row_last];
    if (g_first == g_last) {
        float s8 = ((jv[0][0] + jv[0][1]) + (jv[0][2] + jv[0][3]))
                 + ((jv[1][0] + jv[1][1]) + (jv[1][2] + jv[1][3]));
        s8 += __shfl_xor(s8, 16);
        s8 += __shfl_xor(s8, 32);
        if (lq == 0) atomicAdd(&pooled[g_first * 128 + colj], s8);
    } else {
        #pragma unroll
        for (int mi = 0; mi < 2; ++mi) {
            int rbase = row0 + mi * 16 + lq * 4;
            int gprev = batch[(rbase <= row_last) ? rbase : row_last];
            float run = 0.f;
            #pragma unroll
            for (int rr = 0; rr < 4; ++rr) {
                int gr = rbase + rr;
                int g = batch[(gr <= row_last) ? gr : row_last];
                if (g != gprev) {
                    atomicAdd(&pooled[gprev * 128 + colj], run);
                    run = 0.f; gprev = g;
                }
                run += jv[mi][rr];
            }
            atomicAdd(&pooled[gprev * 128 + colj], run);
        }
    }
}

// ---------------- classifier ----------------

__global__ __launch_bounds__(256) void classifier(const float* __restrict__ pooled,
        const float* __restrict__ Wc1, const float* __restrict__ bc1,
        const float* __restrict__ gamma, const float* __restrict__ beta,
        const float* __restrict__ rmean, const float* __restrict__ rvar,
        const float* __restrict__ Wc2, const float* __restrict__ bc2,
        float* __restrict__ out) {
    int g = blockIdx.x, t = threadIdx.x;
    __shared__ float p[128];
    __shared__ float r0[256], r1[256];
    if (t < 128) p[t] = pooled[g * 128 + t];
    __syncthreads();
    float acc = bc1[t];
    #pragma unroll 8
    for (int k = 0; k < 128; ++k) acc += p[k] * Wc1[k * 256 + t];
    float z = (acc - rmean[t]) * rsqrtf(rvar[t] + 1e-5f) * gamma[t] + beta[t];
    z = fmaxf(z, 0.f);
    r0[t] = z * Wc2[t * 2 + 0];
    r1[t] = z * Wc2[t * 2 + 1];
    __syncthreads();
    for (int s = 128; s > 0; s >>= 1) {
        if (t < s) { r0[t] += r0[t + s]; r1[t] += r1[t + s]; }
        __syncthreads();
    }
    if (t == 0) {
        out[g * 2 + 0] = r0[0] + bc2[0];
        out[g * 2 + 1] = r1[0] + bc2[1];
    }
}

// ---------------- launch ----------------

static inline size_t al256(size_t x) { return (x + 255) & ~size_t(255); }

extern "C" void kernel_launch(void* const* d_in, const int* in_sizes, int n_in,
                              void* d_out, int out_size, void* d_ws, size_t ws_size,
                              hipStream_t stream) {
    const float* x    = (const float*)d_in[0];
    const int*   ei   = (const int*)  d_in[1];
    const int*   batch= (const int*)  d_in[3];
    const float* W0a = (const float*)d_in[4];  const float* b0a = (const float*)d_in[5];
    const float* W0b = (const float*)d_in[6];  const float* b0b = (const float*)d_in[7];
    const float* W1a = (const float*)d_in[8];  const float* b1a = (const float*)d_in[9];
    const float* W1b = (const float*)d_in[10]; const float* b1b = (const float*)d_in[11];
    const float* W2a = (const float*)d_in[12]; const float* b2a = (const float*)d_in[13];
    const float* W2b = (const float*)d_in[14]; const float* b2b = (const float*)d_in[15];
    const float* Wjk = (const float*)d_in[16]; const float* bjk = (const float*)d_in[17];
    const float* Wc1 = (const float*)d_in[18]; const float* bc1 = (const float*)d_in[19];
    const float* gamma=(const float*)d_in[20]; const float* beta= (const float*)d_in[21];
    const float* rmean=(const float*)d_in[22]; const float* rvar= (const float*)d_in[23];
    const float* Wc2 = (const float*)d_in[24]; const float* bc2 = (const float*)d_in[25];
    float* out = (float*)d_out;

    const int N = NN, E = EE, B = BB;

    char* w = (char*)d_ws;
    size_t off = 0;
    int* rowptr = (int*)(w + off); off = al256(off + (size_t)(N + 1) * 4);
    int* bcur2  = (int*)(w + off); off = al256(off + (size_t)NBKT * 4);
    int* bktbase= (int*)(w + off); off = al256(off + (size_t)NBKT * 4);
    int* colarr = (int*)(w + off); off = al256(off + (size_t)E * 4);
    int* ebuf   = (int*)(w + off); off = al256(off + (size_t)NBKT * ESTRIDE * 4);
    ushort* XB1 = (ushort*)(w + off); off = al256(off + (size_t)N * 128 * 2);
    ushort* XB2 = (ushort*)(w + off); off = al256(off + (size_t)N * 128 * 2);
    float* pooled = (float*)(w + off); off = al256(off + (size_t)B * 128 * 4);
    ushort* wfH = (ushort*)(w + off); off = al256(off + (size_t)8 * 16384 * 2);
    ushort* wfL = (ushort*)(w + off); off = al256(off + (size_t)8 * 16384 * 2);

    hipMemsetAsync(bcur2, 0, (size_t)NBKT * 4, stream);
    hipMemsetAsync(pooled, 0, (size_t)B * 128 * 4, stream);

    // pre-split weights (order: W0b, W1a, W1b, W2a, W2b, Wjk0, Wjk1, Wjk2)
    wsplit_all<<<512, 256, 0, stream>>>(W0b, W1a, W1b, W2a, W2b,
                                        Wjk, Wjk + 128 * 128, Wjk + 256 * 128,
                                        wfH, wfL);

    bin_edges4<<<(E + BIN_CHUNK - 1) / BIN_CHUNK, 256, 0, stream>>>(ei, bcur2, ebuf, E);
    bucket_scan<<<1, 512, 0, stream>>>(bcur2, bktbase);
    distribute2<<<NBKT, 256, 0, stream>>>(ebuf, bcur2, bktbase, rowptr, colarr, N, E);

    int gLin = (N + 31) / 32;   // 3125

    // Layer 0: mlp0 (agg7 + lin7 fused in, INMODE2), x1 -> XB1 (bf16)
    mlp_fused<2, false, false, true><<<gLin, 512, 0, stream>>>(
        nullptr, x, W0a, b0a, rowptr, colarr,
        nullptr, nullptr, nullptr,
        wfH + 0 * 16384, wfL + 0 * 16384, b0b,
        wfH + 5 * 16384, wfL + 5 * 16384, nullptr,
        batch, XB1, pooled, N);

    // Layer 1: bf16 gather XB1 -> MLP -> x2 -> XB2 (bf16)
    mlp_fused<1, true, false, true><<<gLin, 512, 0, stream>>>(
        XB1, nullptr, nullptr, nullptr, rowptr, colarr,
        wfH + 1 * 16384, wfL + 1 * 16384, b1a,
        wfH + 2 * 16384, wfL + 2 * 16384, b1b,
        wfH + 6 * 16384, wfL + 6 * 16384, nullptr,
        batch, XB2, pooled, N);

    // Layer 2: bf16 gather XB2 -> MLP -> jk2 (x3 never materialized)
    mlp_fused<1, true, true, false><<<gLin, 512, 0, stream>>>(
        XB2, nullptr, nullptr, nullptr, rowptr, colarr,
        wfH + 3 * 16384, wfL + 3 * 16384, b2a,
        wfH + 4 * 16384, wfL + 4 * 16384, b2b,
        wfH + 7 * 16384, wfL + 7 * 16384, bjk,
        batch, nullptr, pooled, N);

    classifier<<<B, 256, 0, stream>>>(pooled, Wc1, bc1, gamma, beta,
                                      rmean, rvar, Wc2, bc2, out);
}

// Round 12
// 371.866 us; speedup vs baseline: 1.4186x; 1.0007x over previous
//
#include <hip/hip_runtime.h>

#define NN 100000
#define EE 1600000
#define BB 256
#define IN_F 7
#define HH 128
#define NBKT 391        // ceil(NN/256) buckets for binned CSR fill
#define NCHUNK 391      // ceil(EE/BIN_CHUNK)
#define BIN_CHUNK 4096  // edges per binning block
#define ESTRIDE 8192    // fixed ebuf capacity per bucket (mean 4096, sigma 64)

typedef unsigned int uint;
typedef unsigned short ushort;
typedef __attribute__((ext_vector_type(8))) short short8;
typedef __attribute__((ext_vector_type(4))) float f32x4;

// ---------------- bf16 helpers ----------------

__device__ __forceinline__ float bflo(uint u) { return __uint_as_float(u << 16); }
__device__ __forceinline__ float bfhi(uint u) { return __uint_as_float(u & 0xFFFF0000u); }
__device__ __forceinline__ ushort f2bf(float x) {   // RNE; inputs finite
    uint u = __float_as_uint(x);
    u = (u + 0x7FFFu + ((u >> 16) & 1u)) >> 16;
    return (ushort)u;
}

// accumulate 8 bf16 (one uint4) into f[O..O+7]
#define ACC8(F, O, V) \
    F[(O)+0] += bflo((V).x); F[(O)+1] += bfhi((V).x); \
    F[(O)+2] += bflo((V).y); F[(O)+3] += bfhi((V).y); \
    F[(O)+4] += bflo((V).z); F[(O)+5] += bfhi((V).z); \
    F[(O)+6] += bflo((V).w); F[(O)+7] += bfhi((V).w);

// ---------------- fused prep: binning + weight split + x8 pack ----------------
// R25: one kernel, three block ranges. [0,NCHUNK): LDS bucket-sort binning
// (R22). [NCHUNK, NCHUNK+512): wsplit (hi/lo weight fragments). [NCHUNK+512,
// NCHUNK+512+391): pack x [N][7] -> x8 [N][8] f32 zero-padded (for mlp0's
// vectorized aggregation). Independent work fills CUs while binning stalls
// on LDS atomics; two launch boundaries removed.

__global__ __launch_bounds__(256) void prep_fused(const int* __restrict__ ei,
        int* __restrict__ bcur2, int* __restrict__ ebuf,
        const float* __restrict__ w0, const float* __restrict__ w1,
        const float* __restrict__ w2, const float* __restrict__ w3,
        const float* __restrict__ w4, const float* __restrict__ w5,
        const float* __restrict__ w6, const float* __restrict__ w7,
        ushort* __restrict__ hiB, ushort* __restrict__ loB,
        const float* __restrict__ x, float* __restrict__ x8,
        int e, int n) {
    __shared__ int cnt[NBKT];      // counts, then per-bucket cursor
    __shared__ int pref[512];      // inclusive prefix (padded)
    __shared__ int base[NBKT];     // global base per bucket
    __shared__ int sbuf[BIN_CHUNK];// 16 KB staging, bucket-sorted
    int t = threadIdx.x;
    if (blockIdx.x < NCHUNK) {
        int start = blockIdx.x * BIN_CHUNK;
        int end = start + BIN_CHUNK; if (end > e) end = e;
        int m = end - start;
        for (int b = t; b < NBKT; b += 256) cnt[b] = 0;
        __syncthreads();
        for (int i = start + t; i < end; i += 256)
            atomicAdd(&cnt[ei[e + i] >> 8], 1);
        __syncthreads();
        pref[t]       = (t < NBKT) ? cnt[t] : 0;
        pref[t + 256] = (t + 256 < NBKT) ? cnt[t + 256] : 0;
        __syncthreads();
        for (int off = 1; off < 512; off <<= 1) {
            int a0 = (t >= off) ? pref[t - off] : 0;
            int a1 = pref[t + 256 - off];      // t+256 >= off always (off<=256)
            __syncthreads();
            pref[t] += a0;
            pref[t + 256] += a1;
            __syncthreads();
        }
        for (int b = t; b < NBKT; b += 256) {
            int c = cnt[b];
            base[b] = (c > 0) ? atomicAdd(&bcur2[b], c) : 0;
            cnt[b] = 0;
        }
        __syncthreads();
        for (int i = start + t; i < end; i += 256) {
            int d = ei[e + i], s = ei[i];
            int b = d >> 8;
            int lo = (b == 0) ? 0 : pref[b - 1];
            int p = lo + atomicAdd(&cnt[b], 1);
            sbuf[p] = s | ((d & 255) << 17);
        }
        __syncthreads();
        for (int i = t; i < m; i += 256) {
            int loB2 = 0, hiB2 = NBKT - 1;     // smallest b with pref[b] > i
            while (loB2 < hiB2) {
                int mid = (loB2 + hiB2) >> 1;
                if (pref[mid] > i) hiB2 = mid; else loB2 = mid + 1;
            }
            int b = loB2;
            int lofs = (b == 0) ? 0 : pref[b - 1];
            ebuf[b * ESTRIDE + base[b] + (i - lofs)] = sbuf[i];
        }
    } else if (blockIdx.x < NCHUNK + 512) {
        const float* ws[8] = {w0, w1, w2, w3, w4, w5, w6, w7};
        int gidx = (blockIdx.x - NCHUNK) * 256 + t;   // 0..131071
        int mi = gidx >> 14;
        int idx = gidx & 16383;
        int j = idx & 7, l = (idx >> 3) & 63, blk = idx >> 9;
        int kc = blk >> 3, nt = blk & 7;
        int k = kc * 32 + (l >> 4) * 8 + j;
        int nn2 = nt * 16 + (l & 15);
        float f = ws[mi][k * 128 + nn2];
        ushort h = f2bf(f);
        float hf = __uint_as_float((uint)h << 16);
        hiB[gidx] = h;
        loB[gidx] = f2bf(f - hf);
    } else {
        int gid = (blockIdx.x - NCHUNK - 512) * 256 + t;
        if (gid < n) {
            float v[8];
            #pragma unroll
            for (int k = 0; k < 7; ++k) v[k] = x[gid * 7 + k];
            v[7] = 0.f;
            *(float4*)&x8[gid * 8]     = make_float4(v[0], v[1], v[2], v[3]);
            *(float4*)&x8[gid * 8 + 4] = make_float4(v[4], v[5], v[6], v[7]);
        }
    }
}

// R23: exclusive scan of the 391 bucket totals (one block).
__global__ __launch_bounds__(512) void bucket_scan(const int* __restrict__ bcur2,
        int* __restrict__ bktbase) {
    __shared__ int sd[512];
    int t = threadIdx.x;
    int v = (t < NBKT) ? bcur2[t] : 0;
    sd[t] = v; __syncthreads();
    for (int off = 1; off < 512; off <<= 1) {
        int a = (t >= off) ? sd[t - off] : 0;
        __syncthreads();
        sd[t] += a;
        __syncthreads();
    }
    if (t < NBKT) bktbase[t] = sd[t] - v;   // exclusive
}

// R23: one block per bucket. LDS histogram -> 256-wide prefix -> rowptr
// (coalesced) -> LDS-cursor scatter into colarr. Second ebuf read L2-hot.
__global__ __launch_bounds__(256) void distribute2(const int* __restrict__ ebuf,
        const int* __restrict__ bcur2, const int* __restrict__ bktbase,
        int* __restrict__ rowptr, int* __restrict__ colarr, int n, int e) {
    __shared__ int h[256];
    __shared__ int pr[256];
    int b = blockIdx.x, t = threadIdx.x;
    int cntb = bcur2[b];
    int base_b = bktbase[b];
    const int* src = ebuf + (size_t)b * ESTRIDE;
    h[t] = 0;
    __syncthreads();
    for (int i = t; i < cntb; i += 256)
        atomicAdd(&h[(src[i] >> 17) & 255], 1);
    __syncthreads();
    int v = h[t];
    pr[t] = v; __syncthreads();
    for (int off = 1; off < 256; off <<= 1) {
        int a = (t >= off) ? pr[t - off] : 0;
        __syncthreads();
        pr[t] += a;
        __syncthreads();
    }
    int excl = pr[t] - v;
    int node = b * 256 + t;
    if (node <= n) rowptr[node] = base_b + excl;   // node==n -> base+cntb == e
    h[t] = base_b + excl;   // cursor
    __syncthreads();
    for (int i = t; i < cntb; i += 256) {
        int vv = src[i];
        int pos = atomicAdd(&h[(vv >> 17) & 255], 1);
        colarr[pos] = vv & 0x1FFFF;
    }
}

// ------- fused MLP + JK + pool (512 thr = 8 waves, 32-row / 16 KB tile) -------
// R24 gather structure (INMODE 1 unchanged). R25: INMODE 2 aggregation
// vectorized: x8 [N][8] f32, 4 neighbor-halves x 4 float2-lanes per row,
// combined via hl4. JK pooling from registers (R21).

// element (r, cu) lives at bufHL[h][r][ ((cu>>3) ^ (r&7))*8 + (cu&7) ]
__device__ __forceinline__ int swch(int chunk, int r) { return chunk ^ (r & 7); }

__device__ __forceinline__ void gemm_mfma(
        const ushort* __restrict__ WH, const ushort* __restrict__ WL,
        const ushort (&bufHL)[2][32][128], int w, int lm, int lq, int l,
        f32x4 (&acc)[2])
{
    #pragma unroll
    for (int mi = 0; mi < 2; ++mi) acc[mi] = (f32x4){0.f, 0.f, 0.f, 0.f};
    const short8* BH = (const short8*)WH;
    const short8* BL = (const short8*)WL;
    #pragma unroll
    for (int kc = 0; kc < 4; ++kc) {
        short8 bh = BH[(kc * 8 + w) * 64 + l];
        short8 bl = BL[(kc * 8 + w) * 64 + l];
        #pragma unroll
        for (int mi = 0; mi < 2; ++mi) {
            int row = mi * 16 + lm;
            int ch = swch(kc * 4 + lq, row);
            short8 ah = *(const short8*)&bufHL[0][row][ch * 8];
            short8 al = *(const short8*)&bufHL[1][row][ch * 8];
            acc[mi] = __builtin_amdgcn_mfma_f32_16x16x32_bf16(ah, bh, acc[mi], 0, 0, 0);
            acc[mi] = __builtin_amdgcn_mfma_f32_16x16x32_bf16(al, bh, acc[mi], 0, 0, 0);
            acc[mi] = __builtin_amdgcn_mfma_f32_16x16x32_bf16(ah, bl, acc[mi], 0, 0, 0);
        }
    }
}

// relu + bias; write hi/lo back to LDS; optional row-major bf16 XB out
__device__ __forceinline__ void epi_store(f32x4 (&acc)[2], const float* __restrict__ bias,
        ushort (&bufHL)[2][32][128], int row0, int n, int w, int lm, int lq,
        ushort* __restrict__ xout)
{
    int col = w * 16 + lm;
    float bv = bias[col];
    #pragma unroll
    for (int mi = 0; mi < 2; ++mi) {
        #pragma unroll
        for (int rr = 0; rr < 4; ++rr) {
            int row = mi * 16 + lq * 4 + rr;
            int gr = row0 + row;
            float v = fmaxf(acc[mi][rr] + bv, 0.f);
            if (gr >= n) v = 0.f;
            ushort hi = f2bf(v);
            float hf = __uint_as_float((uint)hi << 16);
            ushort lo = f2bf(v - hf);
            int off = (swch(col >> 3, row) << 3) | (col & 7);
            bufHL[0][row][off] = hi;
            bufHL[1][row][off] = lo;
            if (xout != nullptr && gr < n)
                xout[(size_t)gr * 128 + col] = hi;
        }
    }
}

template<int INMODE, bool DO_A, bool LASTB, bool WRITE_X>
__global__ __launch_bounds__(512, 8) void mlp_fused(
        const ushort* __restrict__ in_bf,
        const float* __restrict__ x8in, const float* __restrict__ W0a,
        const float* __restrict__ b0a,
        const int* __restrict__ rowptr, const int* __restrict__ colarr,
        const ushort* __restrict__ WaH, const ushort* __restrict__ WaL,
        const float* __restrict__ ba,
        const ushort* __restrict__ WbH, const ushort* __restrict__ WbL,
        const float* __restrict__ bb,
        const ushort* __restrict__ WjH, const ushort* __restrict__ WjL,
        const float* __restrict__ bjk,
        const int* __restrict__ batch,
        ushort* __restrict__ xout_bf, float* __restrict__ pooled, int n)
{
    __shared__ __align__(16) ushort bufHL[2][32][128];   // 16 KB (hi | lo)
    __shared__ float wlds[(INMODE == 2) ? 1024 : 1];     // W0a(896) + b0a(128)
    __shared__ float hl4[(INMODE == 2) ? 32 : 1][4][8];  // 4 KB agg quarters
    int t = threadIdx.x;
    int row0 = blockIdx.x * 32;

    if (INMODE == 1) {
        // R24: 16 threads/row = 8 col-groups x 2 neighbor-halves; each thread
        // covers 32B (f[16]) of the row and walks every other neighbor; the
        // partner (t^8, same wave) holds the other half -> shfl_xor combine.
        int* idx_lds = (int*)&bufHL[0][0][0];      // capacity 4096 ints (16 KB)
        int rlast = row0 + 32; if (rlast > n) rlast = n;
        int eb = rowptr[row0];
        int cnt = rowptr[rlast] - eb;
        bool allstaged = (cnt <= 4096);
        int staged = allstaged ? cnt : 0;
        for (int i = t; i < staged; i += 512) idx_lds[i] = colarr[eb + i];
        __syncthreads();

        int r = t >> 4, sub = t & 15;
        int q8 = sub & 7, half = sub >> 3;
        int gr = row0 + r;
        float f[16];
        #pragma unroll
        for (int j = 0; j < 16; ++j) f[j] = 0.f;
        if (gr < n) {
            const uint4* sp = (const uint4*)(in_bf + (size_t)gr * 128);
            if (half == 0) {
                uint4 v0 = sp[2 * q8], v1 = sp[2 * q8 + 1];
                ACC8(f, 0, v0); ACC8(f, 8, v1);
            }
            int beg = rowptr[gr] - eb, end = rowptr[gr + 1] - eb;
            if (allstaged) {
                int j = beg + half;
                for (; j + 3 <= end; j += 4) {         // neighbors j, j+2
                    int s0 = idx_lds[j], s1 = idx_lds[j + 2];
                    const uint4* n0 = (const uint4*)(in_bf + (size_t)s0 * 128);
                    const uint4* n1 = (const uint4*)(in_bf + (size_t)s1 * 128);
                    uint4 a0 = n0[2 * q8], a1 = n0[2 * q8 + 1];
                    uint4 b0 = n1[2 * q8], b1 = n1[2 * q8 + 1];
                    ACC8(f, 0, a0); ACC8(f, 8, a1);
                    ACC8(f, 0, b0); ACC8(f, 8, b1);
                }
                for (; j < end; j += 2) {
                    int s0 = idx_lds[j];
                    const uint4* n0 = (const uint4*)(in_bf + (size_t)s0 * 128);
                    uint4 a0 = n0[2 * q8], a1 = n0[2 * q8 + 1];
                    ACC8(f, 0, a0); ACC8(f, 8, a1);
                }
            } else {
                for (int j = beg + half; j < end; j += 2) {
                    int s0 = colarr[eb + j];
                    const uint4* n0 = (const uint4*)(in_bf + (size_t)s0 * 128);
                    uint4 a0 = n0[2 * q8], a1 = n0[2 * q8 + 1];
                    ACC8(f, 0, a0); ACC8(f, 8, a1);
                }
            }
        }
        __syncthreads();   // all idx_lds reads done before bufHL is overwritten
        #pragma unroll
        for (int i = 0; i < 16; ++i) f[i] += __shfl_xor(f[i], 8);
        if (half == 0) {
            #pragma unroll
            for (int c2 = 0; c2 < 2; ++c2) {
                short8 hi8, lo8;
                #pragma unroll
                for (int j = 0; j < 8; ++j) {
                    float v = f[c2 * 8 + j];
                    ushort h = f2bf(v);
                    hi8[j] = (short)h;
                    lo8[j] = (short)f2bf(v - __uint_as_float((uint)h << 16));
                }
                int ch = swch(2 * q8 + c2, r);
                *(short8*)&bufHL[0][r][ch * 8] = hi8;
                *(short8*)&bufHL[1][r][ch * 8] = lo8;
            }
        }
    } else {
        // INMODE 2 (R25): fused d=7 agg on x8 [N][8] (4 halves x 4 float2
        // lanes per row) + t0 = relu(h @ W0a + b0a).
        int* idx_lds = (int*)&bufHL[0][0][0];      // capacity 4096 ints
        int rlast = row0 + 32; if (rlast > n) rlast = n;
        int eb = rowptr[row0];
        int cnt = rowptr[rlast] - eb;
        bool allstaged = (cnt <= 4096);
        int staged = allstaged ? cnt : 0;
        for (int i = t; i < staged; i += 512) idx_lds[i] = colarr[eb + i];
        for (int l = t; l < 1024; l += 512)
            wlds[l] = (l < 896) ? W0a[l] : b0a[l - 896];
        __syncthreads();
        {
            int r = t >> 4, sub = t & 15, lane2 = sub & 3, half = sub >> 2;
            int gr = row0 + r;
            float a0 = 0.f, a1 = 0.f;
            if (gr < n) {
                const float2* xp = (const float2*)(x8in + (size_t)gr * 8);
                if (half == 0) { float2 s = xp[lane2]; a0 = s.x; a1 = s.y; }
                int beg = rowptr[gr] - eb, end = rowptr[gr + 1] - eb;
                if (allstaged) {
                    int j = beg + half;
                    for (; j + 5 <= end; j += 8) {     // neighbors j, j+4
                        const float2* n0 = (const float2*)(x8in + (size_t)idx_lds[j] * 8);
                        const float2* n1 = (const float2*)(x8in + (size_t)idx_lds[j + 4] * 8);
                        float2 v0 = n0[lane2], v1 = n1[lane2];
                        a0 += v0.x + v1.x; a1 += v0.y + v1.y;
                    }
                    for (; j < end; j += 4) {
                        const float2* n0 = (const float2*)(x8in + (size_t)idx_lds[j] * 8);
                        float2 v0 = n0[lane2];
                        a0 += v0.x; a1 += v0.y;
                    }
                } else {
                    for (int j = beg + half; j < end; j += 4) {
                        const float2* n0 = (const float2*)(x8in + (size_t)colarr[eb + j] * 8);
                        float2 v0 = n0[lane2];
                        a0 += v0.x; a1 += v0.y;
                    }
                }
            }
            hl4[r][half][2 * lane2]     = a0;
            hl4[r][half][2 * lane2 + 1] = a1;
        }
        __syncthreads();   // agg done; idx_lds reads complete
        int r = t >> 4, cs = t & 15;          // row, 8-col chunk
        int gr = row0 + r;
        float h[7];
        #pragma unroll
        for (int k = 0; k < 7; ++k)
            h[k] = (hl4[r][0][k] + hl4[r][1][k]) + (hl4[r][2][k] + hl4[r][3][k]);
        float o[8];
        #pragma unroll
        for (int jj = 0; jj < 8; ++jj) {
            int c = cs * 8 + jj;
            float a = wlds[896 + c];
            #pragma unroll
            for (int k = 0; k < 7; ++k) a += h[k] * wlds[k * 128 + c];
            o[jj] = (gr < n) ? fmaxf(a, 0.f) : 0.f;
        }
        short8 hi8, lo8;
        #pragma unroll
        for (int jj = 0; jj < 8; ++jj) {
            ushort hh = f2bf(o[jj]);
            hi8[jj] = (short)hh;
            lo8[jj] = (short)f2bf(o[jj] - __uint_as_float((uint)hh << 16));
        }
        int ch = swch(cs, r);
        *(short8*)&bufHL[0][r][ch * 8] = hi8;
        *(short8*)&bufHL[1][r][ch * 8] = lo8;
    }
    __syncthreads();

    int w = t >> 6, l = t & 63;
    int lm = l & 15, lq = l >> 4;
    f32x4 acc[2];

    if (DO_A) {
        gemm_mfma(WaH, WaL, bufHL, w, lm, lq, l, acc);
        __syncthreads();
        epi_store(acc, ba, bufHL, row0, n, w, lm, lq, nullptr);
        __syncthreads();
    }

    gemm_mfma(WbH, WbL, bufHL, w, lm, lq, l, acc);
    __syncthreads();
    epi_store(acc, bb, bufHL, row0, n, w, lm, lq, WRITE_X ? xout_bf : nullptr);
    __syncthreads();

    gemm_mfma(WjH, WjL, bufHL, w, lm, lq, l, acc);
    // no LDS use after this point -> no barrier; pool from registers.

    int colj = w * 16 + lm;
    float bvj = LASTB ? bjk[colj] : 0.f;
    float jv[2][4];
    #pragma unroll
    for (int mi = 0; mi < 2; ++mi) {
        #pragma unroll
        for (int rr = 0; rr < 4; ++rr) {
            int gr = row0 + mi * 16 + lq * 4 + rr;
            jv[mi][rr] = (gr < n) ? acc[mi][rr] + bvj : 0.f;
        }
    }
    int row_last = row0 + 31; if (row_last > n - 1) row_last = n - 1;
    int g_first = batch[row0];
    int g_last  = batch[row_last];
    if (g_first == g_last) {
        float s8 = ((jv[0][0] + jv[0][1]) + (jv[0][2] + jv[0][3]))
                 + ((jv[1][0] + jv[1][1]) + (jv[1][2] + jv[1][3]));
        s8 += __shfl_xor(s8, 16);
        s8 += __shfl_xor(s8, 32);
        if (lq == 0) atomicAdd(&pooled[g_first * 128 + colj], s8);
    } else {
        #pragma unroll
        for (int mi = 0; mi < 2; ++mi) {
            int rbase = row0 + mi * 16 + lq * 4;
            int gprev = batch[(rbase <= row_last) ? rbase : row_last];
            float run = 0.f;
            #pragma unroll
            for (int rr = 0; rr < 4; ++rr) {
                int gr = rbase + rr;
                int g = batch[(gr <= row_last) ? gr : row_last];
                if (g != gprev) {
                    atomicAdd(&pooled[gprev * 128 + colj], run);
                    run = 0.f; gprev = g;
                }
                run += jv[mi][rr];
            }
            atomicAdd(&pooled[gprev * 128 + colj], run);
        }
    }
}

// ---------------- classifier ----------------

__global__ __launch_bounds__(256) void classifier(const float* __restrict__ pooled,
        const float* __restrict__ Wc1, const float* __restrict__ bc1,
        const float* __restrict__ gamma, const float* __restrict__ beta,
        const float* __restrict__ rmean, const float* __restrict__ rvar,
        const float* __restrict__ Wc2, const float* __restrict__ bc2,
        float* __restrict__ out) {
    int g = blockIdx.x, t = threadIdx.x;
    __shared__ float p[128];
    __shared__ float r0[256], r1[256];
    if (t < 128) p[t] = pooled[g * 128 + t];
    __syncthreads();
    float acc = bc1[t];
    #pragma unroll 8
    for (int k = 0; k < 128; ++k) acc += p[k] * Wc1[k * 256 + t];
    float z = (acc - rmean[t]) * rsqrtf(rvar[t] + 1e-5f) * gamma[t] + beta[t];
    z = fmaxf(z, 0.f);
    r0[t] = z * Wc2[t * 2 + 0];
    r1[t] = z * Wc2[t * 2 + 1];
    __syncthreads();
    for (int s = 128; s > 0; s >>= 1) {
        if (t < s) { r0[t] += r0[t + s]; r1[t] += r1[t + s]; }
        __syncthreads();
    }
    if (t == 0) {
        out[g * 2 + 0] = r0[0] + bc2[0];
        out[g * 2 + 1] = r1[0] + bc2[1];
    }
}

// ---------------- launch ----------------

static inline size_t al256(size_t x) { return (x + 255) & ~size_t(255); }

extern "C" void kernel_launch(void* const* d_in, const int* in_sizes, int n_in,
                              void* d_out, int out_size, void* d_ws, size_t ws_size,
                              hipStream_t stream) {
    const float* x    = (const float*)d_in[0];
    const int*   ei   = (const int*)  d_in[1];
    const int*   batch= (const int*)  d_in[3];
    const float* W0a = (const float*)d_in[4];  const float* b0a = (const float*)d_in[5];
    const float* W0b = (const float*)d_in[6];  const float* b0b = (const float*)d_in[7];
    const float* W1a = (const float*)d_in[8];  const float* b1a = (const float*)d_in[9];
    const float* W1b = (const float*)d_in[10]; const float* b1b = (const float*)d_in[11];
    const float* W2a = (const float*)d_in[12]; const float* b2a = (const float*)d_in[13];
    const float* W2b = (const float*)d_in[14]; const float* b2b = (const float*)d_in[15];
    const float* Wjk = (const float*)d_in[16]; const float* bjk = (const float*)d_in[17];
    const float* Wc1 = (const float*)d_in[18]; const float* bc1 = (const float*)d_in[19];
    const float* gamma=(const float*)d_in[20]; const float* beta= (const float*)d_in[21];
    const float* rmean=(const float*)d_in[22]; const float* rvar= (const float*)d_in[23];
    const float* Wc2 = (const float*)d_in[24]; const float* bc2 = (const float*)d_in[25];
    float* out = (float*)d_out;

    const int N = NN, E = EE, B = BB;

    char* w = (char*)d_ws;
    size_t off = 0;
    int* rowptr = (int*)(w + off); off = al256(off + (size_t)(N + 1) * 4);
    int* bcur2  = (int*)(w + off); off = al256(off + (size_t)NBKT * 4);
    int* bktbase= (int*)(w + off); off = al256(off + (size_t)NBKT * 4);
    int* colarr = (int*)(w + off); off = al256(off + (size_t)E * 4);
    int* ebuf   = (int*)(w + off); off = al256(off + (size_t)NBKT * ESTRIDE * 4);
    ushort* XB1 = (ushort*)(w + off); off = al256(off + (size_t)N * 128 * 2);
    ushort* XB2 = (ushort*)(w + off); off = al256(off + (size_t)N * 128 * 2);
    float* pooled = (float*)(w + off); off = al256(off + (size_t)B * 128 * 4);
    ushort* wfH = (ushort*)(w + off); off = al256(off + (size_t)8 * 16384 * 2);
    ushort* wfL = (ushort*)(w + off); off = al256(off + (size_t)8 * 16384 * 2);
    float* x8  = (float*)(w + off); off = al256(off + (size_t)N * 8 * 4);

    hipMemsetAsync(bcur2, 0, (size_t)NBKT * 4, stream);
    hipMemsetAsync(pooled, 0, (size_t)B * 128 * 4, stream);

    // fused prep: binning [0,391) | weight split [391,903) | x8 pack [903,1294)
    prep_fused<<<NCHUNK + 512 + 391, 256, 0, stream>>>(
        ei, bcur2, ebuf,
        W0b, W1a, W1b, W2a, W2b, Wjk, Wjk + 128 * 128, Wjk + 256 * 128,
        wfH, wfL, x, x8, E, N);
    bucket_scan<<<1, 512, 0, stream>>>(bcur2, bktbase);
    distribute2<<<NBKT, 256, 0, stream>>>(ebuf, bcur2, bktbase, rowptr, colarr, N, E);

    int gLin = (N + 31) / 32;   // 3125

    // Layer 0: mlp0 (agg + lin7 fused in, INMODE2), x1 -> XB1 (bf16)
    mlp_fused<2, false, false, true><<<gLin, 512, 0, stream>>>(
        nullptr, x8, W0a, b0a, rowptr, colarr,
        nullptr, nullptr, nullptr,
        wfH + 0 * 16384, wfL + 0 * 16384, b0b,
        wfH + 5 * 16384, wfL + 5 * 16384, nullptr,
        batch, XB1, pooled, N);

    // Layer 1: bf16 gather XB1 -> MLP -> x2 -> XB2 (bf16)
    mlp_fused<1, true, false, true><<<gLin, 512, 0, stream>>>(
        XB1, nullptr, nullptr, nullptr, rowptr, colarr,
        wfH + 1 * 16384, wfL + 1 * 16384, b1a,
        wfH + 2 * 16384, wfL + 2 * 16384, b1b,
        wfH + 6 * 16384, wfL + 6 * 16384, nullptr,
        batch, XB2, pooled, N);

    // Layer 2: bf16 gather XB2 -> MLP -> jk2 (x3 never materialized)
    mlp_fused<1, true, true, false><<<gLin, 512, 0, stream>>>(
        XB2, nullptr, nullptr, nullptr, rowptr, colarr,
        wfH + 3 * 16384, wfL + 3 * 16384, b2a,
        wfH + 4 * 16384, wfL + 4 * 16384, b2b,
        wfH + 7 * 16384, wfL + 7 * 16384, bjk,
        batch, nullptr, pooled, N);

    classifier<<<B, 256, 0, stream>>>(pooled, Wc1, bc1, gamma, beta,
                                      rmean, rvar, Wc2, bc2, out);
}